// Round 14
// baseline (69.754 us; speedup 1.0000x reference)
//
#include <hip/hip_runtime.h>
#include <math.h>

#define PI_F 3.14159265358979323846f

typedef __attribute__((ext_vector_type(8))) short short8v;
typedef __attribute__((ext_vector_type(4))) float f32x4;
typedef __attribute__((ext_vector_type(16))) float f32x16;

__device__ __forceinline__ unsigned short f2bf(float f) {
    unsigned int u = __float_as_uint(f);
    u += 0x7fffu + ((u >> 16) & 1u);
    return (unsigned short)(u >> 16);
}

__device__ __forceinline__ unsigned int cvtpk_bf16(float lo, float hi) {
    unsigned int r;
    asm("v_cvt_pk_bf16_f32 %0, %1, %2" : "=v"(r) : "v"(lo), "v"(hi));
    return r;
}

union W8 { unsigned int w[4]; short8v v; };

__device__ __forceinline__ void gload_lds16(const void* g, void* l) {
    __builtin_amdgcn_global_load_lds((const __attribute__((address_space(1))) unsigned int*)g,
                                     (__attribute__((address_space(3))) unsigned int*)l, 16, 0, 0);
}

// ---------------- prep (f32->bf16 + W^T) fused with token scalar path ----------------
__global__ __launch_bounds__(256) void prep_tok(const float* __restrict__ audio,
                                                const float* __restrict__ visual,
                                                const float* __restrict__ Wq,
                                                const float* __restrict__ Wk,
                                                const float* __restrict__ Wv,
                                                const float* __restrict__ Wo,
                                                const float* __restrict__ We,
                                                const float* __restrict__ be,
                                                unsigned short* __restrict__ audio_b,
                                                unsigned short* __restrict__ visual_b,
                                                unsigned short* __restrict__ Wqt,
                                                unsigned short* __restrict__ Wkt,
                                                unsigned short* __restrict__ Wvt,
                                                unsigned short* __restrict__ Wot,
                                                float* __restrict__ scale,
                                                float* __restrict__ coh_tok,
                                                float* __restrict__ ent_tok) {
    __shared__ float tile[32][33];
    const int bid = blockIdx.x;
    if (bid < 1536) {
        const int z = bid >> 8;
        const int x0 = (bid & 15) * 32, y0 = ((bid >> 4) & 15) * 32;
        const int tx = threadIdx.x & 31, ty = threadIdx.x >> 5;
        if (z < 2) {
            const float* src = z ? visual : audio;
            unsigned short* dst = z ? visual_b : audio_b;
#pragma unroll
            for (int i = 0; i < 4; i++) {
                int r = y0 + ty + i * 8;
                dst[r * 512 + x0 + tx] = f2bf(src[r * 512 + x0 + tx]);
            }
        } else {
            const float* src = (z == 2) ? Wq : (z == 3) ? Wk : (z == 4) ? Wv : Wo;
            unsigned short* dst = (z == 2) ? Wqt : (z == 3) ? Wkt : (z == 4) ? Wvt : Wot;
#pragma unroll
            for (int i = 0; i < 4; i++)
                tile[ty + i * 8][tx] = src[(y0 + ty + i * 8) * 512 + x0 + tx];
            __syncthreads();
#pragma unroll
            for (int i = 0; i < 4; i++) {
                int n = x0 + ty + i * 8;
                dst[n * 512 + y0 + tx] = f2bf(tile[tx][ty + i * 8]);
            }
        }
    } else {
        const int t = (bid - 1536) * 4 + (threadIdx.x >> 6);
        const int lane = threadIdx.x & 63;
        float accA[8] = {}, accV[8] = {};
#pragma unroll
        for (int i = 0; i < 8; i++) {
            int k = i * 64 + lane;
            float wa = audio[t * 512 + k], wv = visual[t * 512 + k];
            const float* wrow = &We[k * 512];
#pragma unroll
            for (int c = 0; c < 8; c++) {
                float w = wrow[c];
                accA[c] += wa * w;
                accV[c] += wv * w;
            }
        }
#pragma unroll
        for (int c = 0; c < 8; c++) {
#pragma unroll
            for (int o = 32; o >= 1; o >>= 1) {
                accA[c] += __shfl_xor(accA[c], o);
                accV[c] += __shfl_xor(accV[c], o);
            }
        }
        if (lane == 0) {
            float pa = 1.f, pv = 1.f;
#pragma unroll
            for (int c = 0; c < 8; c++) {
                pa *= cosf((accA[c] + be[c]) * (PI_F * 0.5f));
                pv *= cosf((accV[c] + be[c]) * (PI_F * 0.5f));
            }
            float s0a = pa / (fabsf(pa) + 1e-10f);
            float s0v = pv / (fabsf(pv) + 1e-10f);
            float e = s0a * s0v;
            const float a = 0.7071f;
            float ent0 = a * e;
            float qsum = 2.f * ent0 * ent0;
            float interf = (ent0 < 0.f) ? cosf(2.f * PI_F / 65536.f) : 1.f;
            scale[t] = qsum * interf;
            coh_tok[t] = 2.f * fabsf(ent0);
            float p = (ent0 * ent0) / (qsum + 1e-10f);
            ent_tok[t] = -2.f * p * logf(p + 1e-10f);
        }
    }
}

// ---------------- bf16 MFMA GEMM with LDS staging; f32/bf16/bf16-transposed C ----------------
struct MfmaArgs {
    const unsigned short* A[4];
    const unsigned short* Bt[4];
    const float* bias[4];
    void* C[4];
    int obf[4];
    int otr[4];
};

__global__ __launch_bounds__(256) void gemm_mfma(MfmaArgs args) {
    const int zb = blockIdx.z;
    const unsigned short* __restrict__ A = args.A[zb];
    const unsigned short* __restrict__ Bt = args.Bt[zb];
    const float* __restrict__ bias = args.bias[zb];
    const int otr = args.otr[zb];

    const int n0 = blockIdx.x * 64;
    const int m0 = blockIdx.y * 64;

    __shared__ unsigned short As[64 * 64];
    __shared__ unsigned short Bs[64 * 64];

    const int tid = threadIdx.x;
    const int lane = tid & 63;
    const int wid = tid >> 6;
    const int wr = wid >> 1, wc = wid & 1;
    const int l15 = lane & 15;
    const int lhi = lane >> 4;

    f32x4 acc[2][2] = {};

    for (int kt = 0; kt < 8; kt++) {
        const int k0 = kt * 64;
#pragma unroll
        for (int i = 0; i < 2; i++) {
            int row = i * 32 + wid * 8 + (lane >> 3);
            int pc = lane & 7;
            int lc = pc ^ (row & 7);
            const unsigned short* gA = A + (m0 + row) * 512 + k0 + lc * 8;
            const unsigned short* gB = Bt + (n0 + row) * 512 + k0 + lc * 8;
            gload_lds16(gA, (char*)As + i * 4096 + wid * 1024);
            gload_lds16(gB, (char*)Bs + i * 4096 + wid * 1024);
        }
        __syncthreads();
#pragma unroll
        for (int ks = 0; ks < 2; ks++) {
            short8v a[2], b[2];
            const int lcr = ks * 4 + lhi;
#pragma unroll
            for (int qi = 0; qi < 2; qi++) {
                int row = wr * 32 + qi * 16 + l15;
                int pcc = lcr ^ (row & 7);
                a[qi] = *(const short8v*)((const char*)As + row * 128 + pcc * 16);
            }
#pragma unroll
            for (int nj = 0; nj < 2; nj++) {
                int row = wc * 32 + nj * 16 + l15;
                int pcc = lcr ^ (row & 7);
                b[nj] = *(const short8v*)((const char*)Bs + row * 128 + pcc * 16);
            }
            if (otr) {
#pragma unroll
                for (int qi = 0; qi < 2; qi++)
#pragma unroll
                    for (int nj = 0; nj < 2; nj++)
                        acc[qi][nj] = __builtin_amdgcn_mfma_f32_16x16x32_bf16(b[nj], a[qi], acc[qi][nj], 0, 0, 0);
            } else {
#pragma unroll
                for (int qi = 0; qi < 2; qi++)
#pragma unroll
                    for (int nj = 0; nj < 2; nj++)
                        acc[qi][nj] = __builtin_amdgcn_mfma_f32_16x16x32_bf16(a[qi], b[nj], acc[qi][nj], 0, 0, 0);
            }
        }
        __syncthreads();
    }

    if (otr) {
        unsigned short* __restrict__ Ct = (unsigned short*)args.C[zb];
#pragma unroll
        for (int qi = 0; qi < 2; qi++)
#pragma unroll
            for (int nj = 0; nj < 2; nj++)
#pragma unroll
                for (int r = 0; r < 4; r++) {
                    int nrow = n0 + wc * 32 + nj * 16 + lhi * 4 + r;
                    int tcol = m0 + wr * 32 + qi * 16 + l15;
                    Ct[nrow * 512 + tcol] = f2bf(acc[qi][nj][r] + bias[nrow]);
                }
    } else if (args.obf[zb]) {
        unsigned short* __restrict__ Cb = (unsigned short*)args.C[zb];
#pragma unroll
        for (int qi = 0; qi < 2; qi++)
#pragma unroll
            for (int nj = 0; nj < 2; nj++)
#pragma unroll
                for (int r = 0; r < 4; r++) {
                    int row = m0 + wr * 32 + qi * 16 + lhi * 4 + r;
                    int col = n0 + wc * 32 + nj * 16 + l15;
                    Cb[row * 512 + col] = f2bf(acc[qi][nj][r] + bias[col]);
                }
    } else {
        float* __restrict__ C = (float*)args.C[zb];
#pragma unroll
        for (int qi = 0; qi < 2; qi++)
#pragma unroll
            for (int nj = 0; nj < 2; nj++)
#pragma unroll
                for (int r = 0; r < 4; r++) {
                    int row = m0 + wr * 32 + qi * 16 + lhi * 4 + r;
                    int col = n0 + wc * 32 + nj * 16 + l15;
                    C[row * 512 + col] = acc[qi][nj][r] + bias[col];
                }
    }
}

// ---------------- attention, role-split (r13-validated, verbatim) ----------------
__global__ __launch_bounds__(512, 2) void attn_roles(const unsigned short* __restrict__ aqb,
                                                     const unsigned short* __restrict__ vkb,
                                                     const unsigned short* __restrict__ vvt,
                                                     const unsigned short* __restrict__ avt,
                                                     const float* __restrict__ scale,
                                                     const float* __restrict__ coh,
                                                     const float* __restrict__ entt,
                                                     unsigned short* __restrict__ attcat_b,
                                                     float* __restrict__ attn_last,
                                                     float* __restrict__ scal_out) {
    __shared__ char smem[65536];
    char* Kb = smem;
    char* VF = smem + 32768;

    const int tid = threadIdx.x;
    const int wid = tid >> 6;
    const int lane = tid & 63;
    const int lq = lane & 31;
    const int hi = lane >> 5;

    if (blockIdx.x == 8) {
        if (blockIdx.y || blockIdx.z) return;
        float c = coh[tid], e = entt[tid];
#pragma unroll
        for (int o = 32; o >= 1; o >>= 1) {
            c += __shfl_xor(c, o);
            e += __shfl_xor(e, o);
        }
        float* rc = (float*)smem;
        float* re = rc + 8;
        if (lane == 0) { rc[wid] = c; re[wid] = e; }
        __syncthreads();
        if (tid == 0) {
            float cs = 0.f, es = 0.f;
#pragma unroll
            for (int i = 0; i < 8; i++) { cs += rc[i]; es += re[i]; }
            scal_out[0] = cs / (512.f * 65536.f);
            scal_out[1] = es / 512.f;
        }
        return;
    }

    const int h = blockIdx.x, b = blockIdx.y, role = blockIdx.z;

    {
#pragma unroll
        for (int i = 0; i < 4; i++) {
            int r = wid * 32 + i * 8 + (lane >> 3);
            int lc = (lane & 7) ^ (r & 7);
            gload_lds16(vkb + (size_t)(b * 256 + r) * 512 + h * 64 + lc * 8,
                        Kb + wid * 4096 + i * 1024);
        }
    }

    if (role == 0) {
#pragma unroll
        for (int i = 0; i < 4; i++) {
            gload_lds16(vvt + (size_t)(h * 64 + 32 * hi + lq) * 512 + b * 256 + 32 * wid + 8 * i,
                        VF + wid * 4096 + i * 1024);
        }
    }
    __syncthreads();

    f32x16 p[8] = {};
    {
        short8v qf[4];
        const unsigned short* qbase = aqb + (size_t)(b * 256 + wid * 32 + lq) * 512 + h * 64;
#pragma unroll
        for (int s = 0; s < 4; s++) qf[s] = *(const short8v*)(qbase + (2 * s + hi) * 8);
#pragma unroll
        for (int t = 0; t < 8; t++) {
            const int krow = t * 32 + lq;
#pragma unroll
            for (int s = 0; s < 4; s++) {
                int slot = (2 * s + hi) ^ (krow & 7);
                short8v kf = *(const short8v*)(Kb + krow * 128 + (slot << 4));
                p[t] = __builtin_amdgcn_mfma_f32_32x32x16_bf16(kf, qf[s], p[t], 0, 0, 0);
            }
        }
    }

    {
        const float sq = scale[b * 256 + wid * 32 + lq] * 0.125f;
        float mx = -1e30f;
#pragma unroll
        for (int t = 0; t < 8; t++) {
            p[t] *= sq;
#pragma unroll
            for (int r = 0; r < 16; r++) mx = fmaxf(mx, p[t][r]);
        }
        mx = fmaxf(mx, __shfl_xor(mx, 32));
        float sum = 0.f;
#pragma unroll
        for (int t = 0; t < 8; t++)
#pragma unroll
            for (int r = 0; r < 16; r++) {
                float e = __expf(p[t][r] - mx);
                p[t][r] = e;
                sum += e;
            }
        sum += __shfl_xor(sum, 32);
        float inv = 1.0f / sum;
#pragma unroll
        for (int t = 0; t < 8; t++) p[t] *= inv;
    }

    if (role == 0) {
        f32x16 aacc[2] = {};
#pragma unroll
        for (int t = 0; t < 8; t++) {
            unsigned int c0 = cvtpk_bf16(p[t][0], p[t][1]);
            unsigned int c1 = cvtpk_bf16(p[t][2], p[t][3]);
            unsigned int c2 = cvtpk_bf16(p[t][4], p[t][5]);
            unsigned int c3 = cvtpk_bf16(p[t][6], p[t][7]);
            unsigned int e0 = (unsigned int)__shfl_xor((int)c0, 32);
            unsigned int e1 = (unsigned int)__shfl_xor((int)c1, 32);
            unsigned int e2 = (unsigned int)__shfl_xor((int)c2, 32);
            unsigned int e3 = (unsigned int)__shfl_xor((int)c3, 32);
            W8 fa0;
            fa0.w[0] = hi ? e2 : c0;
            fa0.w[1] = hi ? e3 : c1;
            fa0.w[2] = hi ? c2 : e0;
            fa0.w[3] = hi ? c3 : e1;
            unsigned int c4 = cvtpk_bf16(p[t][8], p[t][9]);
            unsigned int c5 = cvtpk_bf16(p[t][10], p[t][11]);
            unsigned int c6 = cvtpk_bf16(p[t][12], p[t][13]);
            unsigned int c7 = cvtpk_bf16(p[t][14], p[t][15]);
            unsigned int e4 = (unsigned int)__shfl_xor((int)c4, 32);
            unsigned int e5 = (unsigned int)__shfl_xor((int)c5, 32);
            unsigned int e6 = (unsigned int)__shfl_xor((int)c6, 32);
            unsigned int e7 = (unsigned int)__shfl_xor((int)c7, 32);
            W8 fa1;
            fa1.w[0] = hi ? e6 : c4;
            fa1.w[1] = hi ? e7 : c5;
            fa1.w[2] = hi ? c6 : e4;
            fa1.w[3] = hi ? c7 : e5;
#pragma unroll
            for (int dt = 0; dt < 2; dt++) {
                short8v vf = *(const short8v*)(VF + ((((t * 4 + hi) * 2 + dt) * 32 + lq) << 4));
                aacc[dt] = __builtin_amdgcn_mfma_f32_32x32x16_bf16(fa0.v, vf, aacc[dt], 0, 0, 0);
                short8v vg = *(const short8v*)(VF + ((((t * 4 + hi + 2) * 2 + dt) * 32 + lq) << 4));
                aacc[dt] = __builtin_amdgcn_mfma_f32_32x32x16_bf16(fa1.v, vg, aacc[dt], 0, 0, 0);
            }
        }
#pragma unroll
        for (int dt = 0; dt < 2; dt++)
#pragma unroll
            for (int r = 0; r < 16; r++) {
                int qrow = wid * 32 + (r & 3) + 8 * (r >> 2) + 4 * hi;
                attcat_b[(size_t)(b * 256 + qrow) * 512 + h * 64 + 32 * dt + lq] = f2bf(aacc[dt][r]);
            }
        __syncthreads();

        if (h == 7) {
            float* tile = (float*)smem + (size_t)wid * (32 * 33);
            const int q2 = lane >> 1, koff = (lane & 1) * 16;
#pragma unroll
            for (int t = 0; t < 8; t++) {
#pragma unroll
                for (int r = 0; r < 16; r++)
                    tile[lq * 33 + ((r & 3) + 8 * (r >> 2) + 4 * hi)] = p[t][r];
                __syncthreads();
                float* orow = attn_last + (size_t)(b * 256 + wid * 32 + q2) * 256 + 32 * t + koff;
#pragma unroll
                for (int j = 0; j < 16; j++) orow[j] = tile[q2 * 33 + koff + j];
                __syncthreads();
            }
        }
        return;
    }

    __syncthreads();

    {
#pragma unroll
        for (int i = 0; i < 4; i++) {
            gload_lds16(avt + (size_t)(h * 64 + 32 * hi + lq) * 512 + b * 256 + 8 * (wid * 4 + i),
                        Kb + wid * 4096 + i * 1024);
        }
        if ((wid >> 1) == 0) {
            const int dq = (wid & 1) * 32 + lq;
#pragma unroll
            for (int t = 0; t < 8; t++)
#pragma unroll
                for (int r = 0; r < 16; r++) {
                    int k = 32 * t + (r & 3) + 8 * (r >> 2) + 4 * hi;
                    int slot = (dq >> 3) ^ ((k ^ (k >> 3)) & 7);
                    *(unsigned short*)(VF + k * 128 + slot * 16 + (dq & 7) * 2) = f2bf(p[t][r]);
                }
        }
    }
    __syncthreads();

    f32x16 vacc[2] = {};
    {
        const int krow = wid * 32 + lq;
        const int xr = (krow ^ (krow >> 3)) & 7;
#pragma unroll
        for (int c = 0; c < 4; c++) {
#pragma unroll
            for (int uc = 0; uc < 4; uc++) {
                int slot = (2 * uc + hi) ^ xr;
                short8v pa = *(const short8v*)(VF + krow * 128 + slot * 16);
                int m = 2 * (4 * c + uc) + hi;
#pragma unroll
                for (int dt = 0; dt < 2; dt++) {
                    short8v af = *(const short8v*)(Kb + (((m * 2 + dt) * 32 + lq) << 4));
                    vacc[dt] = __builtin_amdgcn_mfma_f32_32x32x16_bf16(pa, af, vacc[dt], 0, 0, 0);
                }
            }
            if (c < 3) {
                __syncthreads();
                if ((wid >> 1) == c + 1) {
                    const int dq = (wid & 1) * 32 + lq;
#pragma unroll
                    for (int t = 0; t < 8; t++)
#pragma unroll
                        for (int r = 0; r < 16; r++) {
                            int k = 32 * t + (r & 3) + 8 * (r >> 2) + 4 * hi;
                            int slot = (dq >> 3) ^ ((k ^ (k >> 3)) & 7);
                            *(unsigned short*)(VF + k * 128 + slot * 16 + (dq & 7) * 2) = f2bf(p[t][r]);
                        }
                }
                __syncthreads();
            }
        }
    }
#pragma unroll
    for (int dt = 0; dt < 2; dt++)
#pragma unroll
        for (int r = 0; r < 16; r++) {
            int krow = wid * 32 + (r & 3) + 8 * (r >> 2) + 4 * hi;
            attcat_b[(size_t)(512 + b * 256 + krow) * 512 + h * 64 + 32 * dt + lq] = f2bf(vacc[dt][r]);
        }
}

// ---------------- fused output projection + residual + LayerNorm ----------------
// 16 blocks x 256 thr; block = 64 token rows, full 512 cols. Wave wid owns 16 rows.
// K-accumulation order per element identical to old gemm2 (kt 0..7, ks 0..1) -> proj bit-identical.
__global__ __launch_bounds__(256, 1) void gemm2_ln(const unsigned short* __restrict__ A,
                                                   const unsigned short* __restrict__ Bt,
                                                   const float* __restrict__ bias,
                                                   const float* __restrict__ audio,
                                                   const float* __restrict__ visual,
                                                   const float* __restrict__ gamma,
                                                   const float* __restrict__ beta,
                                                   float* __restrict__ out) {
    __shared__ unsigned short As[64 * 64];   // 8KB
    __shared__ unsigned short Bs[256 * 64];  // 32KB
    __shared__ float gb[512 * 3];            // gamma | beta | bias

    const int m0 = blockIdx.x * 64;
    const int tid = threadIdx.x;
    const int lane = tid & 63;
    const int wid = tid >> 6;
    const int l15 = lane & 15;
    const int lhi = lane >> 4;

    for (int i = tid; i < 512; i += 256) {
        gb[i] = gamma[i];
        gb[512 + i] = beta[i];
        gb[1024 + i] = bias[i];
    }

    f32x4 acc[2][16] = {};

#pragma unroll
    for (int h = 0; h < 2; h++) {
        for (int kt = 0; kt < 8; kt++) {
            const int k0 = kt * 64;
#pragma unroll
            for (int i = 0; i < 2; i++) {
                int row = i * 32 + wid * 8 + (lane >> 3);
                int lc = (lane & 7) ^ (row & 7);
                gload_lds16(A + (size_t)(m0 + row) * 512 + k0 + lc * 8,
                            (char*)As + i * 4096 + wid * 1024);
            }
#pragma unroll
            for (int i = 0; i < 8; i++) {
                int row = wid * 64 + i * 8 + (lane >> 3);
                int lc = (lane & 7) ^ (row & 7);
                gload_lds16(Bt + (size_t)(h * 256 + row) * 512 + k0 + lc * 8,
                            (char*)Bs + wid * 8192 + i * 1024);
            }
            __syncthreads();
#pragma unroll
            for (int ks = 0; ks < 2; ks++) {
                const int lcr = ks * 4 + lhi;
                const int arow = wid * 16 + l15;
                short8v a = *(const short8v*)((const char*)As + arow * 128 + ((lcr ^ (arow & 7)) << 4));
#pragma unroll
                for (int nt = 0; nt < 16; nt++) {
                    int brow = nt * 16 + l15;
                    short8v b = *(const short8v*)((const char*)Bs + brow * 128 + ((lcr ^ (brow & 7)) << 4));
                    acc[h][nt] = __builtin_amdgcn_mfma_f32_16x16x32_bf16(a, b, acc[h][nt], 0, 0, 0);
                }
            }
            __syncthreads();
        }
    }

    // y = x + proj (proj = acc + bias); rows: m0 + wid*16 + lhi*4 + r, col = h*256 + nt*16 + l15
    const float* xbase = (m0 < 512) ? (audio + (size_t)m0 * 512) : (visual + (size_t)(m0 - 512) * 512);
#pragma unroll
    for (int h = 0; h < 2; h++)
#pragma unroll
        for (int nt = 0; nt < 16; nt++) {
            int col = h * 256 + nt * 16 + l15;
            float bc = gb[1024 + col];
#pragma unroll
            for (int r = 0; r < 4; r++) {
                int lrow = wid * 16 + lhi * 4 + r;
                acc[h][nt][r] += bc + xbase[(size_t)lrow * 512 + col];
            }
        }

    // two-pass LN per row (reduce over 32 n-tiles in-regs + 16-lane xor tree)
    float mean[4], rstd[4];
#pragma unroll
    for (int r = 0; r < 4; r++) {
        float s = 0.f;
#pragma unroll
        for (int h = 0; h < 2; h++)
#pragma unroll
            for (int nt = 0; nt < 16; nt++) s += acc[h][nt][r];
#pragma unroll
        for (int o = 1; o < 16; o <<= 1) s += __shfl_xor(s, o);
        mean[r] = s * (1.f / 512.f);
    }
#pragma unroll
    for (int r = 0; r < 4; r++) {
        float v = 0.f;
#pragma unroll
        for (int h = 0; h < 2; h++)
#pragma unroll
            for (int nt = 0; nt < 16; nt++) {
                float d = acc[h][nt][r] - mean[r];
                v += d * d;
            }
#pragma unroll
        for (int o = 1; o < 16; o <<= 1) v += __shfl_xor(v, o);
        rstd[r] = rsqrtf(v * (1.f / 512.f) + 1e-5f);
    }

#pragma unroll
    for (int h = 0; h < 2; h++)
#pragma unroll
        for (int nt = 0; nt < 16; nt++) {
            int col = h * 256 + nt * 16 + l15;
            float g = gb[col], bb = gb[512 + col];
#pragma unroll
            for (int r = 0; r < 4; r++) {
                int row = m0 + wid * 16 + lhi * 4 + r;
                out[(size_t)row * 512 + col] = (acc[h][nt][r] - mean[r]) * rstd[r] * g + bb;
            }
        }
}

extern "C" void kernel_launch(void* const* d_in, const int* in_sizes, int n_in,
                              void* d_out, int out_size, void* d_ws, size_t ws_size,
                              hipStream_t stream) {
    const float* audio  = (const float*)d_in[0];
    const float* visual = (const float*)d_in[1];
    const float* Wq = (const float*)d_in[2];
    const float* bq = (const float*)d_in[3];
    const float* Wk = (const float*)d_in[4];
    const float* bk = (const float*)d_in[5];
    const float* Wv = (const float*)d_in[6];
    const float* bv = (const float*)d_in[7];
    const float* Wo = (const float*)d_in[8];
    const float* bo = (const float*)d_in[9];
    const float* We = (const float*)d_in[10];
    const float* be = (const float*)d_in[11];
    const float* gamma = (const float*)d_in[12];
    const float* beta  = (const float*)d_in[13];
    float* out = (float*)d_out;

    float* ws = (float*)d_ws;
    float* scale = ws;                    // 512
    float* coh   = ws + 512;              // 512
    float* entt  = ws + 1024;             // 512
    unsigned short* attcat_b = (unsigned short*)(ws + 1536);     // 524288 u16
    unsigned short* audio_b  = (unsigned short*)(ws + 263680);   // 262144 u16
    unsigned short* visual_b = (unsigned short*)(ws + 394752);
    unsigned short* Wqt  = (unsigned short*)(ws + 525824);
    unsigned short* Wkt  = (unsigned short*)(ws + 656896);
    unsigned short* Wvt  = (unsigned short*)(ws + 787968);
    unsigned short* Wot  = (unsigned short*)(ws + 919040);
    unsigned short* aq_b = (unsigned short*)(ws + 1050112);      // 262144 u16
    unsigned short* vk_b = (unsigned short*)(ws + 1181184);      // 262144 u16
    unsigned short* vvt  = (unsigned short*)(ws + 1312256);      // 262144 u16
    unsigned short* avt  = (unsigned short*)(ws + 1443328);      // 262144 u16

    // 0) prep (bf16 + W^T) + token scalar path
    hipLaunchKernelGGL(prep_tok, dim3(1664), dim3(256), 0, stream,
                       audio, visual, Wq, Wk, Wv, Wo, We, be,
                       audio_b, visual_b, Wqt, Wkt, Wvt, Wot,
                       scale, coh, entt);

    // 1) projections (MFMA): aq,vk -> bf16; vv,av -> bf16 TRANSPOSED [d][tok]
    MfmaArgs g1;
    g1.A[0] = audio_b;  g1.Bt[0] = Wqt; g1.bias[0] = bq; g1.C[0] = aq_b; g1.obf[0] = 1; g1.otr[0] = 0;
    g1.A[1] = visual_b; g1.Bt[1] = Wkt; g1.bias[1] = bk; g1.C[1] = vk_b; g1.obf[1] = 1; g1.otr[1] = 0;
    g1.A[2] = visual_b; g1.Bt[2] = Wvt; g1.bias[2] = bv; g1.C[2] = vvt;  g1.obf[2] = 1; g1.otr[2] = 1;
    g1.A[3] = audio_b;  g1.Bt[3] = Wvt; g1.bias[3] = bv; g1.C[3] = avt;  g1.obf[3] = 1; g1.otr[3] = 1;
    hipLaunchKernelGGL(gemm_mfma, dim3(8, 8, 4), dim3(256), 0, stream, g1);

    // 2) attention role-split (+ scalar block at x==8)
    hipLaunchKernelGGL(attn_roles, dim3(9, 2, 2), dim3(512), 0, stream,
                       aq_b, vk_b, vvt, avt, scale, coh, entt,
                       attcat_b, out + 524290, out + 524288);

    // 3) fused output projection + residual + LN (writes out directly)
    hipLaunchKernelGGL(gemm2_ln, dim3(16), dim3(256), 0, stream,
                       attcat_b, Wot, bo, audio, visual, gamma, beta, out);
}

// Round 15
// 49.685 us; speedup vs baseline: 1.4039x; 1.4039x over previous
//
#include <hip/hip_runtime.h>
#include <math.h>

#define PI_F 3.14159265358979323846f

typedef __attribute__((ext_vector_type(8))) short short8v;
typedef __attribute__((ext_vector_type(4))) float f32x4;
typedef __attribute__((ext_vector_type(16))) float f32x16;

__device__ __forceinline__ unsigned short f2bf(float f) {
    unsigned int u = __float_as_uint(f);
    u += 0x7fffu + ((u >> 16) & 1u);
    return (unsigned short)(u >> 16);
}

__device__ __forceinline__ unsigned int cvtpk_bf16(float lo, float hi) {
    unsigned int r;
    asm("v_cvt_pk_bf16_f32 %0, %1, %2" : "=v"(r) : "v"(lo), "v"(hi));
    return r;
}

union W8 { unsigned int w[4]; short8v v; };

__device__ __forceinline__ void gload_lds16(const void* g, void* l) {
    __builtin_amdgcn_global_load_lds((const __attribute__((address_space(1))) unsigned int*)g,
                                     (__attribute__((address_space(3))) unsigned int*)l, 16, 0, 0);
}

// ---------------- prep (f32->bf16 + W^T) fused with token scalar path ----------------
__global__ __launch_bounds__(256) void prep_tok(const float* __restrict__ audio,
                                                const float* __restrict__ visual,
                                                const float* __restrict__ Wq,
                                                const float* __restrict__ Wk,
                                                const float* __restrict__ Wv,
                                                const float* __restrict__ Wo,
                                                const float* __restrict__ We,
                                                const float* __restrict__ be,
                                                unsigned short* __restrict__ audio_b,
                                                unsigned short* __restrict__ visual_b,
                                                unsigned short* __restrict__ Wqt,
                                                unsigned short* __restrict__ Wkt,
                                                unsigned short* __restrict__ Wvt,
                                                unsigned short* __restrict__ Wot,
                                                float* __restrict__ scale,
                                                float* __restrict__ coh_tok,
                                                float* __restrict__ ent_tok) {
    __shared__ float tile[32][33];
    const int bid = blockIdx.x;
    if (bid < 1536) {
        const int z = bid >> 8;
        const int x0 = (bid & 15) * 32, y0 = ((bid >> 4) & 15) * 32;
        const int tx = threadIdx.x & 31, ty = threadIdx.x >> 5;
        if (z < 2) {
            const float* src = z ? visual : audio;
            unsigned short* dst = z ? visual_b : audio_b;
#pragma unroll
            for (int i = 0; i < 4; i++) {
                int r = y0 + ty + i * 8;
                dst[r * 512 + x0 + tx] = f2bf(src[r * 512 + x0 + tx]);
            }
        } else {
            const float* src = (z == 2) ? Wq : (z == 3) ? Wk : (z == 4) ? Wv : Wo;
            unsigned short* dst = (z == 2) ? Wqt : (z == 3) ? Wkt : (z == 4) ? Wvt : Wot;
#pragma unroll
            for (int i = 0; i < 4; i++)
                tile[ty + i * 8][tx] = src[(y0 + ty + i * 8) * 512 + x0 + tx];
            __syncthreads();
#pragma unroll
            for (int i = 0; i < 4; i++) {
                int n = x0 + ty + i * 8;
                dst[n * 512 + y0 + tx] = f2bf(tile[tx][ty + i * 8]);
            }
        }
    } else {
        const int t = (bid - 1536) * 4 + (threadIdx.x >> 6);
        const int lane = threadIdx.x & 63;
        float accA[8] = {}, accV[8] = {};
#pragma unroll
        for (int i = 0; i < 8; i++) {
            int k = i * 64 + lane;
            float wa = audio[t * 512 + k], wv = visual[t * 512 + k];
            const float* wrow = &We[k * 512];
#pragma unroll
            for (int c = 0; c < 8; c++) {
                float w = wrow[c];
                accA[c] += wa * w;
                accV[c] += wv * w;
            }
        }
#pragma unroll
        for (int c = 0; c < 8; c++) {
#pragma unroll
            for (int o = 32; o >= 1; o >>= 1) {
                accA[c] += __shfl_xor(accA[c], o);
                accV[c] += __shfl_xor(accV[c], o);
            }
        }
        if (lane == 0) {
            float pa = 1.f, pv = 1.f;
#pragma unroll
            for (int c = 0; c < 8; c++) {
                pa *= cosf((accA[c] + be[c]) * (PI_F * 0.5f));
                pv *= cosf((accV[c] + be[c]) * (PI_F * 0.5f));
            }
            float s0a = pa / (fabsf(pa) + 1e-10f);
            float s0v = pv / (fabsf(pv) + 1e-10f);
            float e = s0a * s0v;
            const float a = 0.7071f;
            float ent0 = a * e;
            float qsum = 2.f * ent0 * ent0;
            float interf = (ent0 < 0.f) ? cosf(2.f * PI_F / 65536.f) : 1.f;
            scale[t] = qsum * interf;
            coh_tok[t] = 2.f * fabsf(ent0);
            float p = (ent0 * ent0) / (qsum + 1e-10f);
            ent_tok[t] = -2.f * p * logf(p + 1e-10f);
        }
    }
}

// ---------------- bf16 MFMA GEMM, BK=128 (4 barriered K-iters); f32/bf16/bf16^T C ----------------
// LDS row = 256B = 16 chunks; phys slot = logical chunk ^ (row & 15).
// K-accumulation order k = kt*128 + ks*32 (0,32,...,480) — identical to BK=64 version.
struct MfmaArgs {
    const unsigned short* A[4];
    const unsigned short* Bt[4];
    const float* bias[4];
    void* C[4];
    int obf[4];
    int otr[4];
};

__global__ __launch_bounds__(256) void gemm_mfma(MfmaArgs args) {
    const int zb = blockIdx.z;
    const unsigned short* __restrict__ A = args.A[zb];
    const unsigned short* __restrict__ Bt = args.Bt[zb];
    const float* __restrict__ bias = args.bias[zb];
    const int otr = args.otr[zb];

    const int n0 = blockIdx.x * 64;
    const int m0 = blockIdx.y * 64;

    __shared__ unsigned short As[64 * 128];  // 16KB
    __shared__ unsigned short Bs[64 * 128];  // 16KB

    const int tid = threadIdx.x;
    const int lane = tid & 63;
    const int wid = tid >> 6;
    const int wr = wid >> 1, wc = wid & 1;
    const int l15 = lane & 15;
    const int lhi = lane >> 4;

    // staging: chunk L = i*256 + tid -> row r = i*16 + (tid>>4), phys slot = tid&15;
    // logical chunk lc = slot ^ (r & 15) = (tid&15) ^ ((tid>>4)&15)
    const int sRow = tid >> 4;              // row-within-64 per i-block offset base
    const int lcS = (tid & 15) ^ (sRow & 15);

    f32x4 acc[2][2] = {};

    for (int kt = 0; kt < 4; kt++) {
        const int k0 = kt * 128;
#pragma unroll
        for (int i = 0; i < 4; i++) {
            int r = i * 16 + sRow;
            gload_lds16(A + (size_t)(m0 + r) * 512 + k0 + lcS * 8,
                        (char*)As + i * 4096 + wid * 1024);
            gload_lds16(Bt + (size_t)(n0 + r) * 512 + k0 + lcS * 8,
                        (char*)Bs + i * 4096 + wid * 1024);
        }
        __syncthreads();
#pragma unroll
        for (int ks = 0; ks < 4; ks++) {
            short8v a[2], b[2];
            const int lcr = ks * 4 + lhi;   // 0..15
#pragma unroll
            for (int qi = 0; qi < 2; qi++) {
                int row = wr * 32 + qi * 16 + l15;
                int slot = lcr ^ (row & 15);
                a[qi] = *(const short8v*)((const char*)As + row * 256 + slot * 16);
            }
#pragma unroll
            for (int nj = 0; nj < 2; nj++) {
                int row = wc * 32 + nj * 16 + l15;
                int slot = lcr ^ (row & 15);
                b[nj] = *(const short8v*)((const char*)Bs + row * 256 + slot * 16);
            }
            if (otr) {
#pragma unroll
                for (int qi = 0; qi < 2; qi++)
#pragma unroll
                    for (int nj = 0; nj < 2; nj++)
                        acc[qi][nj] = __builtin_amdgcn_mfma_f32_16x16x32_bf16(b[nj], a[qi], acc[qi][nj], 0, 0, 0);
            } else {
#pragma unroll
                for (int qi = 0; qi < 2; qi++)
#pragma unroll
                    for (int nj = 0; nj < 2; nj++)
                        acc[qi][nj] = __builtin_amdgcn_mfma_f32_16x16x32_bf16(a[qi], b[nj], acc[qi][nj], 0, 0, 0);
            }
        }
        __syncthreads();
    }

    if (otr) {
        unsigned short* __restrict__ Ct = (unsigned short*)args.C[zb];
#pragma unroll
        for (int qi = 0; qi < 2; qi++)
#pragma unroll
            for (int nj = 0; nj < 2; nj++)
#pragma unroll
                for (int r = 0; r < 4; r++) {
                    int nrow = n0 + wc * 32 + nj * 16 + lhi * 4 + r;
                    int tcol = m0 + wr * 32 + qi * 16 + l15;
                    Ct[nrow * 512 + tcol] = f2bf(acc[qi][nj][r] + bias[nrow]);
                }
    } else if (args.obf[zb]) {
        unsigned short* __restrict__ Cb = (unsigned short*)args.C[zb];
#pragma unroll
        for (int qi = 0; qi < 2; qi++)
#pragma unroll
            for (int nj = 0; nj < 2; nj++)
#pragma unroll
                for (int r = 0; r < 4; r++) {
                    int row = m0 + wr * 32 + qi * 16 + lhi * 4 + r;
                    int col = n0 + wc * 32 + nj * 16 + l15;
                    Cb[row * 512 + col] = f2bf(acc[qi][nj][r] + bias[col]);
                }
    } else {
        float* __restrict__ C = (float*)args.C[zb];
#pragma unroll
        for (int qi = 0; qi < 2; qi++)
#pragma unroll
            for (int nj = 0; nj < 2; nj++)
#pragma unroll
                for (int r = 0; r < 4; r++) {
                    int row = m0 + wr * 32 + qi * 16 + lhi * 4 + r;
                    int col = n0 + wc * 32 + nj * 16 + l15;
                    C[row * 512 + col] = acc[qi][nj][r] + bias[col];
                }
    }
}

// ---------------- attention, role-split (r13-validated; h7 tile barriers removed) ----------------
__global__ __launch_bounds__(512, 2) void attn_roles(const unsigned short* __restrict__ aqb,
                                                     const unsigned short* __restrict__ vkb,
                                                     const unsigned short* __restrict__ vvt,
                                                     const unsigned short* __restrict__ avt,
                                                     const float* __restrict__ scale,
                                                     const float* __restrict__ coh,
                                                     const float* __restrict__ entt,
                                                     unsigned short* __restrict__ attcat_b,
                                                     float* __restrict__ attn_last,
                                                     float* __restrict__ scal_out) {
    __shared__ char smem[65536];
    char* Kb = smem;
    char* VF = smem + 32768;

    const int tid = threadIdx.x;
    const int wid = tid >> 6;
    const int lane = tid & 63;
    const int lq = lane & 31;
    const int hi = lane >> 5;

    if (blockIdx.x == 8) {
        if (blockIdx.y || blockIdx.z) return;
        float c = coh[tid], e = entt[tid];
#pragma unroll
        for (int o = 32; o >= 1; o >>= 1) {
            c += __shfl_xor(c, o);
            e += __shfl_xor(e, o);
        }
        float* rc = (float*)smem;
        float* re = rc + 8;
        if (lane == 0) { rc[wid] = c; re[wid] = e; }
        __syncthreads();
        if (tid == 0) {
            float cs = 0.f, es = 0.f;
#pragma unroll
            for (int i = 0; i < 8; i++) { cs += rc[i]; es += re[i]; }
            scal_out[0] = cs / (512.f * 65536.f);
            scal_out[1] = es / 512.f;
        }
        return;
    }

    const int h = blockIdx.x, b = blockIdx.y, role = blockIdx.z;

    {
#pragma unroll
        for (int i = 0; i < 4; i++) {
            int r = wid * 32 + i * 8 + (lane >> 3);
            int lc = (lane & 7) ^ (r & 7);
            gload_lds16(vkb + (size_t)(b * 256 + r) * 512 + h * 64 + lc * 8,
                        Kb + wid * 4096 + i * 1024);
        }
    }

    if (role == 0) {
#pragma unroll
        for (int i = 0; i < 4; i++) {
            gload_lds16(vvt + (size_t)(h * 64 + 32 * hi + lq) * 512 + b * 256 + 32 * wid + 8 * i,
                        VF + wid * 4096 + i * 1024);
        }
    }
    __syncthreads();

    f32x16 p[8] = {};
    {
        short8v qf[4];
        const unsigned short* qbase = aqb + (size_t)(b * 256 + wid * 32 + lq) * 512 + h * 64;
#pragma unroll
        for (int s = 0; s < 4; s++) qf[s] = *(const short8v*)(qbase + (2 * s + hi) * 8);
#pragma unroll
        for (int t = 0; t < 8; t++) {
            const int krow = t * 32 + lq;
#pragma unroll
            for (int s = 0; s < 4; s++) {
                int slot = (2 * s + hi) ^ (krow & 7);
                short8v kf = *(const short8v*)(Kb + krow * 128 + (slot << 4));
                p[t] = __builtin_amdgcn_mfma_f32_32x32x16_bf16(kf, qf[s], p[t], 0, 0, 0);
            }
        }
    }

    {
        const float sq = scale[b * 256 + wid * 32 + lq] * 0.125f;
        float mx = -1e30f;
#pragma unroll
        for (int t = 0; t < 8; t++) {
            p[t] *= sq;
#pragma unroll
            for (int r = 0; r < 16; r++) mx = fmaxf(mx, p[t][r]);
        }
        mx = fmaxf(mx, __shfl_xor(mx, 32));
        float sum = 0.f;
#pragma unroll
        for (int t = 0; t < 8; t++)
#pragma unroll
            for (int r = 0; r < 16; r++) {
                float e = __expf(p[t][r] - mx);
                p[t][r] = e;
                sum += e;
            }
        sum += __shfl_xor(sum, 32);
        float inv = 1.0f / sum;
#pragma unroll
        for (int t = 0; t < 8; t++) p[t] *= inv;
    }

    if (role == 0) {
        f32x16 aacc[2] = {};
#pragma unroll
        for (int t = 0; t < 8; t++) {
            unsigned int c0 = cvtpk_bf16(p[t][0], p[t][1]);
            unsigned int c1 = cvtpk_bf16(p[t][2], p[t][3]);
            unsigned int c2 = cvtpk_bf16(p[t][4], p[t][5]);
            unsigned int c3 = cvtpk_bf16(p[t][6], p[t][7]);
            unsigned int e0 = (unsigned int)__shfl_xor((int)c0, 32);
            unsigned int e1 = (unsigned int)__shfl_xor((int)c1, 32);
            unsigned int e2 = (unsigned int)__shfl_xor((int)c2, 32);
            unsigned int e3 = (unsigned int)__shfl_xor((int)c3, 32);
            W8 fa0;
            fa0.w[0] = hi ? e2 : c0;
            fa0.w[1] = hi ? e3 : c1;
            fa0.w[2] = hi ? c2 : e0;
            fa0.w[3] = hi ? c3 : e1;
            unsigned int c4 = cvtpk_bf16(p[t][8], p[t][9]);
            unsigned int c5 = cvtpk_bf16(p[t][10], p[t][11]);
            unsigned int c6 = cvtpk_bf16(p[t][12], p[t][13]);
            unsigned int c7 = cvtpk_bf16(p[t][14], p[t][15]);
            unsigned int e4 = (unsigned int)__shfl_xor((int)c4, 32);
            unsigned int e5 = (unsigned int)__shfl_xor((int)c5, 32);
            unsigned int e6 = (unsigned int)__shfl_xor((int)c6, 32);
            unsigned int e7 = (unsigned int)__shfl_xor((int)c7, 32);
            W8 fa1;
            fa1.w[0] = hi ? e6 : c4;
            fa1.w[1] = hi ? e7 : c5;
            fa1.w[2] = hi ? c6 : e4;
            fa1.w[3] = hi ? c7 : e5;
#pragma unroll
            for (int dt = 0; dt < 2; dt++) {
                short8v vf = *(const short8v*)(VF + ((((t * 4 + hi) * 2 + dt) * 32 + lq) << 4));
                aacc[dt] = __builtin_amdgcn_mfma_f32_32x32x16_bf16(fa0.v, vf, aacc[dt], 0, 0, 0);
                short8v vg = *(const short8v*)(VF + ((((t * 4 + hi + 2) * 2 + dt) * 32 + lq) << 4));
                aacc[dt] = __builtin_amdgcn_mfma_f32_32x32x16_bf16(fa1.v, vg, aacc[dt], 0, 0, 0);
            }
        }
#pragma unroll
        for (int dt = 0; dt < 2; dt++)
#pragma unroll
            for (int r = 0; r < 16; r++) {
                int qrow = wid * 32 + (r & 3) + 8 * (r >> 2) + 4 * hi;
                attcat_b[(size_t)(b * 256 + qrow) * 512 + h * 64 + 32 * dt + lq] = f2bf(aacc[dt][r]);
            }
        __syncthreads();  // all Kb/VF reads complete; smem free for per-wave tiles

        if (h == 7) {
            // per-wave private tile; intra-wave LDS ordering is automatic -> no barriers
            float* tile = (float*)smem + (size_t)wid * (32 * 33);
            const int q2 = lane >> 1, koff = (lane & 1) * 16;
#pragma unroll
            for (int t = 0; t < 8; t++) {
#pragma unroll
                for (int r = 0; r < 16; r++)
                    tile[lq * 33 + ((r & 3) + 8 * (r >> 2) + 4 * hi)] = p[t][r];
                float* orow = attn_last + (size_t)(b * 256 + wid * 32 + q2) * 256 + 32 * t + koff;
#pragma unroll
                for (int j = 0; j < 16; j++) orow[j] = tile[q2 * 33 + koff + j];
            }
        }
        return;
    }

    __syncthreads();

    {
#pragma unroll
        for (int i = 0; i < 4; i++) {
            gload_lds16(avt + (size_t)(h * 64 + 32 * hi + lq) * 512 + b * 256 + 8 * (wid * 4 + i),
                        Kb + wid * 4096 + i * 1024);
        }
        if ((wid >> 1) == 0) {
            const int dq = (wid & 1) * 32 + lq;
#pragma unroll
            for (int t = 0; t < 8; t++)
#pragma unroll
                for (int r = 0; r < 16; r++) {
                    int k = 32 * t + (r & 3) + 8 * (r >> 2) + 4 * hi;
                    int slot = (dq >> 3) ^ ((k ^ (k >> 3)) & 7);
                    *(unsigned short*)(VF + k * 128 + slot * 16 + (dq & 7) * 2) = f2bf(p[t][r]);
                }
        }
    }
    __syncthreads();

    f32x16 vacc[2] = {};
    {
        const int krow = wid * 32 + lq;
        const int xr = (krow ^ (krow >> 3)) & 7;
#pragma unroll
        for (int c = 0; c < 4; c++) {
#pragma unroll
            for (int uc = 0; uc < 4; uc++) {
                int slot = (2 * uc + hi) ^ xr;
                short8v pa = *(const short8v*)(VF + krow * 128 + slot * 16);
                int m = 2 * (4 * c + uc) + hi;
#pragma unroll
                for (int dt = 0; dt < 2; dt++) {
                    short8v af = *(const short8v*)(Kb + (((m * 2 + dt) * 32 + lq) << 4));
                    vacc[dt] = __builtin_amdgcn_mfma_f32_32x32x16_bf16(pa, af, vacc[dt], 0, 0, 0);
                }
            }
            if (c < 3) {
                __syncthreads();
                if ((wid >> 1) == c + 1) {
                    const int dq = (wid & 1) * 32 + lq;
#pragma unroll
                    for (int t = 0; t < 8; t++)
#pragma unroll
                        for (int r = 0; r < 16; r++) {
                            int k = 32 * t + (r & 3) + 8 * (r >> 2) + 4 * hi;
                            int slot = (dq >> 3) ^ ((k ^ (k >> 3)) & 7);
                            *(unsigned short*)(VF + k * 128 + slot * 16 + (dq & 7) * 2) = f2bf(p[t][r]);
                        }
                }
                __syncthreads();
            }
        }
    }
#pragma unroll
    for (int dt = 0; dt < 2; dt++)
#pragma unroll
        for (int r = 0; r < 16; r++) {
            int krow = wid * 32 + (r & 3) + 8 * (r >> 2) + 4 * hi;
            attcat_b[(size_t)(512 + b * 256 + krow) * 512 + h * 64 + 32 * dt + lq] = f2bf(vacc[dt][r]);
        }
}

// ---------------- residual + LayerNorm ----------------
__global__ __launch_bounds__(256) void ln_final(const float* __restrict__ xa,
                                                const float* __restrict__ xv,
                                                const float* __restrict__ proj,
                                                const float* __restrict__ gamma,
                                                const float* __restrict__ beta,
                                                float* __restrict__ out) {
    __shared__ float red[4];
    const int t = blockIdx.x;
    const int tid = threadIdx.x;
    const int wid = tid >> 6, lane = tid & 63;

    const float* x = (t < 512) ? (xa + t * 512) : (xv + (t - 512) * 512);
    const float* pp = proj + t * 512;

    float y0 = x[tid] + pp[tid];
    float y1 = x[tid + 256] + pp[tid + 256];

    float s = y0 + y1;
#pragma unroll
    for (int o = 32; o >= 1; o >>= 1) s += __shfl_xor(s, o);
    if (lane == 0) red[wid] = s;
    __syncthreads();
    float mean = (red[0] + red[1] + red[2] + red[3]) * (1.f / 512.f);

    float d0 = y0 - mean, d1 = y1 - mean;
    float v = d0 * d0 + d1 * d1;
    __syncthreads();
#pragma unroll
    for (int o = 32; o >= 1; o >>= 1) v += __shfl_xor(v, o);
    if (lane == 0) red[wid] = v;
    __syncthreads();
    float var = (red[0] + red[1] + red[2] + red[3]) * (1.f / 512.f);
    float rstd = rsqrtf(var + 1e-5f);

    out[t * 512 + tid] = d0 * rstd * gamma[tid] + beta[tid];
    out[t * 512 + tid + 256] = d1 * rstd * gamma[tid + 256] + beta[tid + 256];
}

extern "C" void kernel_launch(void* const* d_in, const int* in_sizes, int n_in,
                              void* d_out, int out_size, void* d_ws, size_t ws_size,
                              hipStream_t stream) {
    const float* audio  = (const float*)d_in[0];
    const float* visual = (const float*)d_in[1];
    const float* Wq = (const float*)d_in[2];
    const float* bq = (const float*)d_in[3];
    const float* Wk = (const float*)d_in[4];
    const float* bk = (const float*)d_in[5];
    const float* Wv = (const float*)d_in[6];
    const float* bv = (const float*)d_in[7];
    const float* Wo = (const float*)d_in[8];
    const float* bo = (const float*)d_in[9];
    const float* We = (const float*)d_in[10];
    const float* be = (const float*)d_in[11];
    const float* gamma = (const float*)d_in[12];
    const float* beta  = (const float*)d_in[13];
    float* out = (float*)d_out;

    float* ws = (float*)d_ws;
    float* proj  = ws;                    // 524288 f32
    float* scale = ws + 524288;           // 512
    float* coh   = ws + 524800;           // 512
    float* entt  = ws + 525312;           // 512
    unsigned short* attcat_b = (unsigned short*)(ws + 525824);   // 524288 u16
    unsigned short* audio_b  = (unsigned short*)(ws + 787968);   // 262144 u16
    unsigned short* visual_b = (unsigned short*)(ws + 919040);
    unsigned short* Wqt  = (unsigned short*)(ws + 1050112);
    unsigned short* Wkt  = (unsigned short*)(ws + 1181184);
    unsigned short* Wvt  = (unsigned short*)(ws + 1312256);
    unsigned short* Wot  = (unsigned short*)(ws + 1443328);
    unsigned short* aq_b = (unsigned short*)(ws + 1574400);      // 262144 u16
    unsigned short* vk_b = (unsigned short*)(ws + 1705472);      // 262144 u16
    unsigned short* vvt  = (unsigned short*)(ws + 1836544);      // 262144 u16 [512 d][512 tok]
    unsigned short* avt  = (unsigned short*)(ws + 1967616);      // 262144 u16

    // 0) prep (bf16 + W^T) + token scalar path
    hipLaunchKernelGGL(prep_tok, dim3(1664), dim3(256), 0, stream,
                       audio, visual, Wq, Wk, Wv, Wo, We, be,
                       audio_b, visual_b, Wqt, Wkt, Wvt, Wot,
                       scale, coh, entt);

    // 1) projections (MFMA, BK=128): aq,vk -> bf16; vv,av -> bf16 TRANSPOSED [d][tok]
    MfmaArgs g1;
    g1.A[0] = audio_b;  g1.Bt[0] = Wqt; g1.bias[0] = bq; g1.C[0] = aq_b; g1.obf[0] = 1; g1.otr[0] = 0;
    g1.A[1] = visual_b; g1.Bt[1] = Wkt; g1.bias[1] = bk; g1.C[1] = vk_b; g1.obf[1] = 1; g1.otr[1] = 0;
    g1.A[2] = visual_b; g1.Bt[2] = Wvt; g1.bias[2] = bv; g1.C[2] = vvt;  g1.obf[2] = 1; g1.otr[2] = 1;
    g1.A[3] = audio_b;  g1.Bt[3] = Wvt; g1.bias[3] = bv; g1.C[3] = avt;  g1.obf[3] = 1; g1.otr[3] = 1;
    hipLaunchKernelGGL(gemm_mfma, dim3(8, 8, 4), dim3(256), 0, stream, g1);

    // 2) attention role-split (+ scalar block at x==8)
    hipLaunchKernelGGL(attn_roles, dim3(9, 2, 2), dim3(512), 0, stream,
                       aq_b, vk_b, vvt, avt, scale, coh, entt,
                       attcat_b, out + 524290, out + 524288);

    // 3) output projection (MFMA, BK=128): proj = attcat @ Wo + bo   (M=1024, f32 out)
    MfmaArgs g2;
    for (int i = 0; i < 4; i++) {
        g2.A[i] = attcat_b; g2.Bt[i] = Wot; g2.bias[i] = bo; g2.C[i] = proj;
        g2.obf[i] = 0; g2.otr[i] = 0;
    }
    hipLaunchKernelGGL(gemm_mfma, dim3(8, 16, 1), dim3(256), 0, stream, g2);

    // 4) residual + LN
    hipLaunchKernelGGL(ln_final, dim3(1024), dim3(256), 0, stream,
                       audio, visual, proj, gamma, beta, out);
}

// Round 16
// 48.188 us; speedup vs baseline: 1.4476x; 1.0311x over previous
//
#include <hip/hip_runtime.h>
#include <math.h>

#define PI_F 3.14159265358979323846f

typedef __attribute__((ext_vector_type(8))) short short8v;
typedef __attribute__((ext_vector_type(4))) float f32x4;
typedef __attribute__((ext_vector_type(16))) float f32x16;

__device__ __forceinline__ unsigned short f2bf(float f) {
    unsigned int u = __float_as_uint(f);
    u += 0x7fffu + ((u >> 16) & 1u);
    return (unsigned short)(u >> 16);
}

__device__ __forceinline__ unsigned int cvtpk_bf16(float lo, float hi) {
    unsigned int r;
    asm("v_cvt_pk_bf16_f32 %0, %1, %2" : "=v"(r) : "v"(lo), "v"(hi));
    return r;
}

union W8 { unsigned int w[4]; short8v v; };

__device__ __forceinline__ void gload_lds16(const void* g, void* l) {
    __builtin_amdgcn_global_load_lds((const __attribute__((address_space(1))) unsigned int*)g,
                                     (__attribute__((address_space(3))) unsigned int*)l, 16, 0, 0);
}

// ---------------- prep (f32->bf16 + W^T) fused with token scalar path ----------------
__global__ __launch_bounds__(256) void prep_tok(const float* __restrict__ audio,
                                                const float* __restrict__ visual,
                                                const float* __restrict__ Wq,
                                                const float* __restrict__ Wk,
                                                const float* __restrict__ Wv,
                                                const float* __restrict__ Wo,
                                                const float* __restrict__ We,
                                                const float* __restrict__ be,
                                                unsigned short* __restrict__ audio_b,
                                                unsigned short* __restrict__ visual_b,
                                                unsigned short* __restrict__ Wqt,
                                                unsigned short* __restrict__ Wkt,
                                                unsigned short* __restrict__ Wvt,
                                                unsigned short* __restrict__ Wot,
                                                float* __restrict__ scale,
                                                float* __restrict__ coh_tok,
                                                float* __restrict__ ent_tok) {
    __shared__ float tile[32][33];
    const int bid = blockIdx.x;
    if (bid < 1536) {
        const int z = bid >> 8;
        const int x0 = (bid & 15) * 32, y0 = ((bid >> 4) & 15) * 32;
        const int tx = threadIdx.x & 31, ty = threadIdx.x >> 5;
        if (z < 2) {
            const float* src = z ? visual : audio;
            unsigned short* dst = z ? visual_b : audio_b;
#pragma unroll
            for (int i = 0; i < 4; i++) {
                int r = y0 + ty + i * 8;
                dst[r * 512 + x0 + tx] = f2bf(src[r * 512 + x0 + tx]);
            }
        } else {
            const float* src = (z == 2) ? Wq : (z == 3) ? Wk : (z == 4) ? Wv : Wo;
            unsigned short* dst = (z == 2) ? Wqt : (z == 3) ? Wkt : (z == 4) ? Wvt : Wot;
#pragma unroll
            for (int i = 0; i < 4; i++)
                tile[ty + i * 8][tx] = src[(y0 + ty + i * 8) * 512 + x0 + tx];
            __syncthreads();
#pragma unroll
            for (int i = 0; i < 4; i++) {
                int n = x0 + ty + i * 8;
                dst[n * 512 + y0 + tx] = f2bf(tile[tx][ty + i * 8]);
            }
        }
    } else {
        const int t = (bid - 1536) * 4 + (threadIdx.x >> 6);
        const int lane = threadIdx.x & 63;
        float accA[8] = {}, accV[8] = {};
#pragma unroll
        for (int i = 0; i < 8; i++) {
            int k = i * 64 + lane;
            float wa = audio[t * 512 + k], wv = visual[t * 512 + k];
            const float* wrow = &We[k * 512];
#pragma unroll
            for (int c = 0; c < 8; c++) {
                float w = wrow[c];
                accA[c] += wa * w;
                accV[c] += wv * w;
            }
        }
#pragma unroll
        for (int c = 0; c < 8; c++) {
#pragma unroll
            for (int o = 32; o >= 1; o >>= 1) {
                accA[c] += __shfl_xor(accA[c], o);
                accV[c] += __shfl_xor(accV[c], o);
            }
        }
        if (lane == 0) {
            float pa = 1.f, pv = 1.f;
#pragma unroll
            for (int c = 0; c < 8; c++) {
                pa *= cosf((accA[c] + be[c]) * (PI_F * 0.5f));
                pv *= cosf((accV[c] + be[c]) * (PI_F * 0.5f));
            }
            float s0a = pa / (fabsf(pa) + 1e-10f);
            float s0v = pv / (fabsf(pv) + 1e-10f);
            float e = s0a * s0v;
            const float a = 0.7071f;
            float ent0 = a * e;
            float qsum = 2.f * ent0 * ent0;
            float interf = (ent0 < 0.f) ? cosf(2.f * PI_F / 65536.f) : 1.f;
            scale[t] = qsum * interf;
            coh_tok[t] = 2.f * fabsf(ent0);
            float p = (ent0 * ent0) / (qsum + 1e-10f);
            ent_tok[t] = -2.f * p * logf(p + 1e-10f);
        }
    }
}

// ---------------- bf16 MFMA GEMM, 32x32 tile, BK=512 (ONE barriered stage) ----------------
// LDS row = 1024B = 64 chunks; phys slot = logical chunk ^ row (row 0..31).
// Wave wid stages row i*4+wid per i (64 lanes = 64 chunks, linear dest).
// K-accumulation order k = ks*32 (0,32,...,480) — identical to r15.
struct MfmaArgs {
    const unsigned short* A[4];
    const unsigned short* Bt[4];
    const float* bias[4];
    void* C[4];
    int obf[4];
    int otr[4];
};

__global__ __launch_bounds__(256) void gemm_mfma(MfmaArgs args) {
    const int zb = blockIdx.z;
    const unsigned short* __restrict__ A = args.A[zb];
    const unsigned short* __restrict__ Bt = args.Bt[zb];
    const float* __restrict__ bias = args.bias[zb];
    const int otr = args.otr[zb];

    const int n0 = blockIdx.x * 32;
    const int m0 = blockIdx.y * 32;

    __shared__ unsigned short As[32 * 512];  // 32KB
    __shared__ unsigned short Bs[32 * 512];  // 32KB

    const int tid = threadIdx.x;
    const int lane = tid & 63;
    const int wid = tid >> 6;
    const int wr = wid >> 1, wc = wid & 1;
    const int l15 = lane & 15;
    const int lhi = lane >> 4;

    // stage all 512 K at once: per i, wave wid owns row i*4+wid (one 1024B row)
#pragma unroll
    for (int i = 0; i < 8; i++) {
        int row = i * 4 + wid;
        int lc = lane ^ row;                 // logical chunk (phys slot = lane)
        gload_lds16(A + (size_t)(m0 + row) * 512 + lc * 8,
                    (char*)As + row * 1024);
        gload_lds16(Bt + (size_t)(n0 + row) * 512 + lc * 8,
                    (char*)Bs + row * 1024);
    }
    __syncthreads();

    f32x4 acc = {};
    const int arow = wr * 16 + l15;
    const int brow = wc * 16 + l15;
#pragma unroll
    for (int ks = 0; ks < 16; ks++) {
        const int lcr = ks * 4 + lhi;        // 0..63
        short8v a = *(const short8v*)((const char*)As + arow * 1024 + ((lcr ^ arow) << 4));
        short8v b = *(const short8v*)((const char*)Bs + brow * 1024 + ((lcr ^ brow) << 4));
        if (otr)
            acc = __builtin_amdgcn_mfma_f32_16x16x32_bf16(b, a, acc, 0, 0, 0);
        else
            acc = __builtin_amdgcn_mfma_f32_16x16x32_bf16(a, b, acc, 0, 0, 0);
    }

    if (otr) {
        unsigned short* __restrict__ Ct = (unsigned short*)args.C[zb];
#pragma unroll
        for (int r = 0; r < 4; r++) {
            int nrow = n0 + wc * 16 + lhi * 4 + r;
            int tcol = m0 + wr * 16 + l15;
            Ct[nrow * 512 + tcol] = f2bf(acc[r] + bias[nrow]);
        }
    } else if (args.obf[zb]) {
        unsigned short* __restrict__ Cb = (unsigned short*)args.C[zb];
#pragma unroll
        for (int r = 0; r < 4; r++) {
            int row = m0 + wr * 16 + lhi * 4 + r;
            int col = n0 + wc * 16 + l15;
            Cb[row * 512 + col] = f2bf(acc[r] + bias[col]);
        }
    } else {
        float* __restrict__ C = (float*)args.C[zb];
#pragma unroll
        for (int r = 0; r < 4; r++) {
            int row = m0 + wr * 16 + lhi * 4 + r;
            int col = n0 + wc * 16 + l15;
            C[row * 512 + col] = acc[r] + bias[col];
        }
    }
}

// ---------------- attention, role-split (r15-validated, verbatim) ----------------
__global__ __launch_bounds__(512, 2) void attn_roles(const unsigned short* __restrict__ aqb,
                                                     const unsigned short* __restrict__ vkb,
                                                     const unsigned short* __restrict__ vvt,
                                                     const unsigned short* __restrict__ avt,
                                                     const float* __restrict__ scale,
                                                     const float* __restrict__ coh,
                                                     const float* __restrict__ entt,
                                                     unsigned short* __restrict__ attcat_b,
                                                     float* __restrict__ attn_last,
                                                     float* __restrict__ scal_out) {
    __shared__ char smem[65536];
    char* Kb = smem;
    char* VF = smem + 32768;

    const int tid = threadIdx.x;
    const int wid = tid >> 6;
    const int lane = tid & 63;
    const int lq = lane & 31;
    const int hi = lane >> 5;

    if (blockIdx.x == 8) {
        if (blockIdx.y || blockIdx.z) return;
        float c = coh[tid], e = entt[tid];
#pragma unroll
        for (int o = 32; o >= 1; o >>= 1) {
            c += __shfl_xor(c, o);
            e += __shfl_xor(e, o);
        }
        float* rc = (float*)smem;
        float* re = rc + 8;
        if (lane == 0) { rc[wid] = c; re[wid] = e; }
        __syncthreads();
        if (tid == 0) {
            float cs = 0.f, es = 0.f;
#pragma unroll
            for (int i = 0; i < 8; i++) { cs += rc[i]; es += re[i]; }
            scal_out[0] = cs / (512.f * 65536.f);
            scal_out[1] = es / 512.f;
        }
        return;
    }

    const int h = blockIdx.x, b = blockIdx.y, role = blockIdx.z;

    {
#pragma unroll
        for (int i = 0; i < 4; i++) {
            int r = wid * 32 + i * 8 + (lane >> 3);
            int lc = (lane & 7) ^ (r & 7);
            gload_lds16(vkb + (size_t)(b * 256 + r) * 512 + h * 64 + lc * 8,
                        Kb + wid * 4096 + i * 1024);
        }
    }

    if (role == 0) {
#pragma unroll
        for (int i = 0; i < 4; i++) {
            gload_lds16(vvt + (size_t)(h * 64 + 32 * hi + lq) * 512 + b * 256 + 32 * wid + 8 * i,
                        VF + wid * 4096 + i * 1024);
        }
    }
    __syncthreads();

    f32x16 p[8] = {};
    {
        short8v qf[4];
        const unsigned short* qbase = aqb + (size_t)(b * 256 + wid * 32 + lq) * 512 + h * 64;
#pragma unroll
        for (int s = 0; s < 4; s++) qf[s] = *(const short8v*)(qbase + (2 * s + hi) * 8);
#pragma unroll
        for (int t = 0; t < 8; t++) {
            const int krow = t * 32 + lq;
#pragma unroll
            for (int s = 0; s < 4; s++) {
                int slot = (2 * s + hi) ^ (krow & 7);
                short8v kf = *(const short8v*)(Kb + krow * 128 + (slot << 4));
                p[t] = __builtin_amdgcn_mfma_f32_32x32x16_bf16(kf, qf[s], p[t], 0, 0, 0);
            }
        }
    }

    {
        const float sq = scale[b * 256 + wid * 32 + lq] * 0.125f;
        float mx = -1e30f;
#pragma unroll
        for (int t = 0; t < 8; t++) {
            p[t] *= sq;
#pragma unroll
            for (int r = 0; r < 16; r++) mx = fmaxf(mx, p[t][r]);
        }
        mx = fmaxf(mx, __shfl_xor(mx, 32));
        float sum = 0.f;
#pragma unroll
        for (int t = 0; t < 8; t++)
#pragma unroll
            for (int r = 0; r < 16; r++) {
                float e = __expf(p[t][r] - mx);
                p[t][r] = e;
                sum += e;
            }
        sum += __shfl_xor(sum, 32);
        float inv = 1.0f / sum;
#pragma unroll
        for (int t = 0; t < 8; t++) p[t] *= inv;
    }

    if (role == 0) {
        f32x16 aacc[2] = {};
#pragma unroll
        for (int t = 0; t < 8; t++) {
            unsigned int c0 = cvtpk_bf16(p[t][0], p[t][1]);
            unsigned int c1 = cvtpk_bf16(p[t][2], p[t][3]);
            unsigned int c2 = cvtpk_bf16(p[t][4], p[t][5]);
            unsigned int c3 = cvtpk_bf16(p[t][6], p[t][7]);
            unsigned int e0 = (unsigned int)__shfl_xor((int)c0, 32);
            unsigned int e1 = (unsigned int)__shfl_xor((int)c1, 32);
            unsigned int e2 = (unsigned int)__shfl_xor((int)c2, 32);
            unsigned int e3 = (unsigned int)__shfl_xor((int)c3, 32);
            W8 fa0;
            fa0.w[0] = hi ? e2 : c0;
            fa0.w[1] = hi ? e3 : c1;
            fa0.w[2] = hi ? c2 : e0;
            fa0.w[3] = hi ? c3 : e1;
            unsigned int c4 = cvtpk_bf16(p[t][8], p[t][9]);
            unsigned int c5 = cvtpk_bf16(p[t][10], p[t][11]);
            unsigned int c6 = cvtpk_bf16(p[t][12], p[t][13]);
            unsigned int c7 = cvtpk_bf16(p[t][14], p[t][15]);
            unsigned int e4 = (unsigned int)__shfl_xor((int)c4, 32);
            unsigned int e5 = (unsigned int)__shfl_xor((int)c5, 32);
            unsigned int e6 = (unsigned int)__shfl_xor((int)c6, 32);
            unsigned int e7 = (unsigned int)__shfl_xor((int)c7, 32);
            W8 fa1;
            fa1.w[0] = hi ? e6 : c4;
            fa1.w[1] = hi ? e7 : c5;
            fa1.w[2] = hi ? c6 : e4;
            fa1.w[3] = hi ? c7 : e5;
#pragma unroll
            for (int dt = 0; dt < 2; dt++) {
                short8v vf = *(const short8v*)(VF + ((((t * 4 + hi) * 2 + dt) * 32 + lq) << 4));
                aacc[dt] = __builtin_amdgcn_mfma_f32_32x32x16_bf16(fa0.v, vf, aacc[dt], 0, 0, 0);
                short8v vg = *(const short8v*)(VF + ((((t * 4 + hi + 2) * 2 + dt) * 32 + lq) << 4));
                aacc[dt] = __builtin_amdgcn_mfma_f32_32x32x16_bf16(fa1.v, vg, aacc[dt], 0, 0, 0);
            }
        }
#pragma unroll
        for (int dt = 0; dt < 2; dt++)
#pragma unroll
            for (int r = 0; r < 16; r++) {
                int qrow = wid * 32 + (r & 3) + 8 * (r >> 2) + 4 * hi;
                attcat_b[(size_t)(b * 256 + qrow) * 512 + h * 64 + 32 * dt + lq] = f2bf(aacc[dt][r]);
            }
        __syncthreads();

        if (h == 7) {
            float* tile = (float*)smem + (size_t)wid * (32 * 33);
            const int q2 = lane >> 1, koff = (lane & 1) * 16;
#pragma unroll
            for (int t = 0; t < 8; t++) {
#pragma unroll
                for (int r = 0; r < 16; r++)
                    tile[lq * 33 + ((r & 3) + 8 * (r >> 2) + 4 * hi)] = p[t][r];
                float* orow = attn_last + (size_t)(b * 256 + wid * 32 + q2) * 256 + 32 * t + koff;
#pragma unroll
                for (int j = 0; j < 16; j++) orow[j] = tile[q2 * 33 + koff + j];
            }
        }
        return;
    }

    __syncthreads();

    {
#pragma unroll
        for (int i = 0; i < 4; i++) {
            gload_lds16(avt + (size_t)(h * 64 + 32 * hi + lq) * 512 + b * 256 + 8 * (wid * 4 + i),
                        Kb + wid * 4096 + i * 1024);
        }
        if ((wid >> 1) == 0) {
            const int dq = (wid & 1) * 32 + lq;
#pragma unroll
            for (int t = 0; t < 8; t++)
#pragma unroll
                for (int r = 0; r < 16; r++) {
                    int k = 32 * t + (r & 3) + 8 * (r >> 2) + 4 * hi;
                    int slot = (dq >> 3) ^ ((k ^ (k >> 3)) & 7);
                    *(unsigned short*)(VF + k * 128 + slot * 16 + (dq & 7) * 2) = f2bf(p[t][r]);
                }
        }
    }
    __syncthreads();

    f32x16 vacc[2] = {};
    {
        const int krow = wid * 32 + lq;
        const int xr = (krow ^ (krow >> 3)) & 7;
#pragma unroll
        for (int c = 0; c < 4; c++) {
#pragma unroll
            for (int uc = 0; uc < 4; uc++) {
                int slot = (2 * uc + hi) ^ xr;
                short8v pa = *(const short8v*)(VF + krow * 128 + slot * 16);
                int m = 2 * (4 * c + uc) + hi;
#pragma unroll
                for (int dt = 0; dt < 2; dt++) {
                    short8v af = *(const short8v*)(Kb + (((m * 2 + dt) * 32 + lq) << 4));
                    vacc[dt] = __builtin_amdgcn_mfma_f32_32x32x16_bf16(pa, af, vacc[dt], 0, 0, 0);
                }
            }
            if (c < 3) {
                __syncthreads();
                if ((wid >> 1) == c + 1) {
                    const int dq = (wid & 1) * 32 + lq;
#pragma unroll
                    for (int t = 0; t < 8; t++)
#pragma unroll
                        for (int r = 0; r < 16; r++) {
                            int k = 32 * t + (r & 3) + 8 * (r >> 2) + 4 * hi;
                            int slot = (dq >> 3) ^ ((k ^ (k >> 3)) & 7);
                            *(unsigned short*)(VF + k * 128 + slot * 16 + (dq & 7) * 2) = f2bf(p[t][r]);
                        }
                }
                __syncthreads();
            }
        }
    }
#pragma unroll
    for (int dt = 0; dt < 2; dt++)
#pragma unroll
        for (int r = 0; r < 16; r++) {
            int krow = wid * 32 + (r & 3) + 8 * (r >> 2) + 4 * hi;
            attcat_b[(size_t)(512 + b * 256 + krow) * 512 + h * 64 + 32 * dt + lq] = f2bf(vacc[dt][r]);
        }
}

// ---------------- residual + LayerNorm ----------------
__global__ __launch_bounds__(256) void ln_final(const float* __restrict__ xa,
                                                const float* __restrict__ xv,
                                                const float* __restrict__ proj,
                                                const float* __restrict__ gamma,
                                                const float* __restrict__ beta,
                                                float* __restrict__ out) {
    __shared__ float red[4];
    const int t = blockIdx.x;
    const int tid = threadIdx.x;
    const int wid = tid >> 6, lane = tid & 63;

    const float* x = (t < 512) ? (xa + t * 512) : (xv + (t - 512) * 512);
    const float* pp = proj + t * 512;

    float y0 = x[tid] + pp[tid];
    float y1 = x[tid + 256] + pp[tid + 256];

    float s = y0 + y1;
#pragma unroll
    for (int o = 32; o >= 1; o >>= 1) s += __shfl_xor(s, o);
    if (lane == 0) red[wid] = s;
    __syncthreads();
    float mean = (red[0] + red[1] + red[2] + red[3]) * (1.f / 512.f);

    float d0 = y0 - mean, d1 = y1 - mean;
    float v = d0 * d0 + d1 * d1;
    __syncthreads();
#pragma unroll
    for (int o = 32; o >= 1; o >>= 1) v += __shfl_xor(v, o);
    if (lane == 0) red[wid] = v;
    __syncthreads();
    float var = (red[0] + red[1] + red[2] + red[3]) * (1.f / 512.f);
    float rstd = rsqrtf(var + 1e-5f);

    out[t * 512 + tid] = d0 * rstd * gamma[tid] + beta[tid];
    out[t * 512 + tid + 256] = d1 * rstd * gamma[tid + 256] + beta[tid + 256];
}

extern "C" void kernel_launch(void* const* d_in, const int* in_sizes, int n_in,
                              void* d_out, int out_size, void* d_ws, size_t ws_size,
                              hipStream_t stream) {
    const float* audio  = (const float*)d_in[0];
    const float* visual = (const float*)d_in[1];
    const float* Wq = (const float*)d_in[2];
    const float* bq = (const float*)d_in[3];
    const float* Wk = (const float*)d_in[4];
    const float* bk = (const float*)d_in[5];
    const float* Wv = (const float*)d_in[6];
    const float* bv = (const float*)d_in[7];
    const float* Wo = (const float*)d_in[8];
    const float* bo = (const float*)d_in[9];
    const float* We = (const float*)d_in[10];
    const float* be = (const float*)d_in[11];
    const float* gamma = (const float*)d_in[12];
    const float* beta  = (const float*)d_in[13];
    float* out = (float*)d_out;

    float* ws = (float*)d_ws;
    float* proj  = ws;                    // 524288 f32
    float* scale = ws + 524288;           // 512
    float* coh   = ws + 524800;           // 512
    float* entt  = ws + 525312;           // 512
    unsigned short* attcat_b = (unsigned short*)(ws + 525824);   // 524288 u16
    unsigned short* audio_b  = (unsigned short*)(ws + 787968);   // 262144 u16
    unsigned short* visual_b = (unsigned short*)(ws + 919040);
    unsigned short* Wqt  = (unsigned short*)(ws + 1050112);
    unsigned short* Wkt  = (unsigned short*)(ws + 1181184);
    unsigned short* Wvt  = (unsigned short*)(ws + 1312256);
    unsigned short* Wot  = (unsigned short*)(ws + 1443328);
    unsigned short* aq_b = (unsigned short*)(ws + 1574400);      // 262144 u16
    unsigned short* vk_b = (unsigned short*)(ws + 1705472);      // 262144 u16
    unsigned short* vvt  = (unsigned short*)(ws + 1836544);      // 262144 u16 [512 d][512 tok]
    unsigned short* avt  = (unsigned short*)(ws + 1967616);      // 262144 u16

    // 0) prep (bf16 + W^T) + token scalar path
    hipLaunchKernelGGL(prep_tok, dim3(1664), dim3(256), 0, stream,
                       audio, visual, Wq, Wk, Wv, Wo, We, be,
                       audio_b, visual_b, Wqt, Wkt, Wvt, Wot,
                       scale, coh, entt);

    // 1) projections (MFMA, BK=512 single-barrier): aq,vk -> bf16; vv,av -> bf16^T [d][tok]
    MfmaArgs g1;
    g1.A[0] = audio_b;  g1.Bt[0] = Wqt; g1.bias[0] = bq; g1.C[0] = aq_b; g1.obf[0] = 1; g1.otr[0] = 0;
    g1.A[1] = visual_b; g1.Bt[1] = Wkt; g1.bias[1] = bk; g1.C[1] = vk_b; g1.obf[1] = 1; g1.otr[1] = 0;
    g1.A[2] = visual_b; g1.Bt[2] = Wvt; g1.bias[2] = bv; g1.C[2] = vvt;  g1.obf[2] = 1; g1.otr[2] = 1;
    g1.A[3] = audio_b;  g1.Bt[3] = Wvt; g1.bias[3] = bv; g1.C[3] = avt;  g1.obf[3] = 1; g1.otr[3] = 1;
    hipLaunchKernelGGL(gemm_mfma, dim3(16, 16, 4), dim3(256), 0, stream, g1);

    // 2) attention role-split (+ scalar block at x==8)
    hipLaunchKernelGGL(attn_roles, dim3(9, 2, 2), dim3(512), 0, stream,
                       aq_b, vk_b, vvt, avt, scale, coh, entt,
                       attcat_b, out + 524290, out + 524288);

    // 3) output projection (MFMA, BK=512): proj = attcat @ Wo + bo   (M=1024, f32 out)
    MfmaArgs g2;
    for (int i = 0; i < 4; i++) {
        g2.A[i] = attcat_b; g2.Bt[i] = Wot; g2.bias[i] = bo; g2.C[i] = proj;
        g2.obf[i] = 0; g2.otr[i] = 0;
    }
    hipLaunchKernelGGL(gemm_mfma, dim3(16, 32, 1), dim3(256), 0, stream, g2);

    // 4) residual + LN
    hipLaunchKernelGGL(ln_final, dim3(1024), dim3(256), 0, stream,
                       audio, visual, proj, gamma, beta, out);
}

// Round 17
// 47.475 us; speedup vs baseline: 1.4693x; 1.0150x over previous
//
#include <hip/hip_runtime.h>
#include <math.h>

#define PI_F 3.14159265358979323846f

typedef __attribute__((ext_vector_type(8))) short short8v;
typedef __attribute__((ext_vector_type(4))) float f32x4;
typedef __attribute__((ext_vector_type(16))) float f32x16;

__device__ __forceinline__ unsigned short f2bf(float f) {
    unsigned int u = __float_as_uint(f);
    u += 0x7fffu + ((u >> 16) & 1u);
    return (unsigned short)(u >> 16);
}

__device__ __forceinline__ unsigned int cvtpk_bf16(float lo, float hi) {
    unsigned int r;
    asm("v_cvt_pk_bf16_f32 %0, %1, %2" : "=v"(r) : "v"(lo), "v"(hi));
    return r;
}

union W8 { unsigned int w[4]; short8v v; };

__device__ __forceinline__ void gload_lds16(const void* g, void* l) {
    __builtin_amdgcn_global_load_lds((const __attribute__((address_space(1))) unsigned int*)g,
                                     (__attribute__((address_space(3))) unsigned int*)l, 16, 0, 0);
}

// ---------------- prep (f32->bf16 + W^T) fused with token scalar path ----------------
__global__ __launch_bounds__(256) void prep_tok(const float* __restrict__ audio,
                                                const float* __restrict__ visual,
                                                const float* __restrict__ Wq,
                                                const float* __restrict__ Wk,
                                                const float* __restrict__ Wv,
                                                const float* __restrict__ Wo,
                                                const float* __restrict__ We,
                                                const float* __restrict__ be,
                                                unsigned short* __restrict__ audio_b,
                                                unsigned short* __restrict__ visual_b,
                                                unsigned short* __restrict__ Wqt,
                                                unsigned short* __restrict__ Wkt,
                                                unsigned short* __restrict__ Wvt,
                                                unsigned short* __restrict__ Wot,
                                                float* __restrict__ scale,
                                                float* __restrict__ coh_tok,
                                                float* __restrict__ ent_tok) {
    __shared__ float tile[32][33];
    const int bid = blockIdx.x;
    if (bid < 1536) {
        const int z = bid >> 8;
        const int x0 = (bid & 15) * 32, y0 = ((bid >> 4) & 15) * 32;
        const int tx = threadIdx.x & 31, ty = threadIdx.x >> 5;
        if (z < 2) {
            const float* src = z ? visual : audio;
            unsigned short* dst = z ? visual_b : audio_b;
#pragma unroll
            for (int i = 0; i < 4; i++) {
                int r = y0 + ty + i * 8;
                dst[r * 512 + x0 + tx] = f2bf(src[r * 512 + x0 + tx]);
            }
        } else {
            const float* src = (z == 2) ? Wq : (z == 3) ? Wk : (z == 4) ? Wv : Wo;
            unsigned short* dst = (z == 2) ? Wqt : (z == 3) ? Wkt : (z == 4) ? Wvt : Wot;
#pragma unroll
            for (int i = 0; i < 4; i++)
                tile[ty + i * 8][tx] = src[(y0 + ty + i * 8) * 512 + x0 + tx];
            __syncthreads();
#pragma unroll
            for (int i = 0; i < 4; i++) {
                int n = x0 + ty + i * 8;
                dst[n * 512 + y0 + tx] = f2bf(tile[tx][ty + i * 8]);
            }
        }
    } else {
        const int t = (bid - 1536) * 4 + (threadIdx.x >> 6);
        const int lane = threadIdx.x & 63;
        float accA[8] = {}, accV[8] = {};
#pragma unroll
        for (int i = 0; i < 8; i++) {
            int k = i * 64 + lane;
            float wa = audio[t * 512 + k], wv = visual[t * 512 + k];
            const float* wrow = &We[k * 512];
#pragma unroll
            for (int c = 0; c < 8; c++) {
                float w = wrow[c];
                accA[c] += wa * w;
                accV[c] += wv * w;
            }
        }
#pragma unroll
        for (int c = 0; c < 8; c++) {
#pragma unroll
            for (int o = 32; o >= 1; o >>= 1) {
                accA[c] += __shfl_xor(accA[c], o);
                accV[c] += __shfl_xor(accV[c], o);
            }
        }
        if (lane == 0) {
            float pa = 1.f, pv = 1.f;
#pragma unroll
            for (int c = 0; c < 8; c++) {
                pa *= cosf((accA[c] + be[c]) * (PI_F * 0.5f));
                pv *= cosf((accV[c] + be[c]) * (PI_F * 0.5f));
            }
            float s0a = pa / (fabsf(pa) + 1e-10f);
            float s0v = pv / (fabsf(pv) + 1e-10f);
            float e = s0a * s0v;
            const float a = 0.7071f;
            float ent0 = a * e;
            float qsum = 2.f * ent0 * ent0;
            float interf = (ent0 < 0.f) ? cosf(2.f * PI_F / 65536.f) : 1.f;
            scale[t] = qsum * interf;
            coh_tok[t] = 2.f * fabsf(ent0);
            float p = (ent0 * ent0) / (qsum + 1e-10f);
            ent_tok[t] = -2.f * p * logf(p + 1e-10f);
        }
    }
}

// ---------------- bf16 MFMA GEMM, 32x32 tile, BK=512 (ONE barriered stage) ----------------
struct MfmaArgs {
    const unsigned short* A[4];
    const unsigned short* Bt[4];
    const float* bias[4];
    void* C[4];
    int obf[4];
    int otr[4];
};

__global__ __launch_bounds__(256) void gemm_mfma(MfmaArgs args) {
    const int zb = blockIdx.z;
    const unsigned short* __restrict__ A = args.A[zb];
    const unsigned short* __restrict__ Bt = args.Bt[zb];
    const float* __restrict__ bias = args.bias[zb];
    const int otr = args.otr[zb];

    const int n0 = blockIdx.x * 32;
    const int m0 = blockIdx.y * 32;

    __shared__ unsigned short As[32 * 512];  // 32KB
    __shared__ unsigned short Bs[32 * 512];  // 32KB

    const int tid = threadIdx.x;
    const int lane = tid & 63;
    const int wid = tid >> 6;
    const int wr = wid >> 1, wc = wid & 1;
    const int l15 = lane & 15;
    const int lhi = lane >> 4;

#pragma unroll
    for (int i = 0; i < 8; i++) {
        int row = i * 4 + wid;
        int lc = lane ^ row;
        gload_lds16(A + (size_t)(m0 + row) * 512 + lc * 8,
                    (char*)As + row * 1024);
        gload_lds16(Bt + (size_t)(n0 + row) * 512 + lc * 8,
                    (char*)Bs + row * 1024);
    }
    __syncthreads();

    f32x4 acc = {};
    const int arow = wr * 16 + l15;
    const int brow = wc * 16 + l15;
#pragma unroll
    for (int ks = 0; ks < 16; ks++) {
        const int lcr = ks * 4 + lhi;
        short8v a = *(const short8v*)((const char*)As + arow * 1024 + ((lcr ^ arow) << 4));
        short8v b = *(const short8v*)((const char*)Bs + brow * 1024 + ((lcr ^ brow) << 4));
        if (otr)
            acc = __builtin_amdgcn_mfma_f32_16x16x32_bf16(b, a, acc, 0, 0, 0);
        else
            acc = __builtin_amdgcn_mfma_f32_16x16x32_bf16(a, b, acc, 0, 0, 0);
    }

    if (otr) {
        unsigned short* __restrict__ Ct = (unsigned short*)args.C[zb];
#pragma unroll
        for (int r = 0; r < 4; r++) {
            int nrow = n0 + wc * 16 + lhi * 4 + r;
            int tcol = m0 + wr * 16 + l15;
            Ct[nrow * 512 + tcol] = f2bf(acc[r] + bias[nrow]);
        }
    } else if (args.obf[zb]) {
        unsigned short* __restrict__ Cb = (unsigned short*)args.C[zb];
#pragma unroll
        for (int r = 0; r < 4; r++) {
            int row = m0 + wr * 16 + lhi * 4 + r;
            int col = n0 + wc * 16 + l15;
            Cb[row * 512 + col] = f2bf(acc[r] + bias[col]);
        }
    } else {
        float* __restrict__ C = (float*)args.C[zb];
#pragma unroll
        for (int r = 0; r < 4; r++) {
            int row = m0 + wr * 16 + lhi * 4 + r;
            int col = n0 + wc * 16 + l15;
            C[row * 512 + col] = acc[r] + bias[col];
        }
    }
}

// ---------------- attention, role-split + early Q/AV issue (T14 hoisting) ----------------
// Role 0: K->Kb, V->VF staged together; Q frags + scale loaded pre-barrier.
// Role 1: K->Kb, AV->VF staged together (AV latency hidden under QK^T);
//         P^T chunks go through Kb (dead after QK^T, barrier-guarded).
__global__ __launch_bounds__(512, 2) void attn_roles(const unsigned short* __restrict__ aqb,
                                                     const unsigned short* __restrict__ vkb,
                                                     const unsigned short* __restrict__ vvt,
                                                     const unsigned short* __restrict__ avt,
                                                     const float* __restrict__ scale,
                                                     const float* __restrict__ coh,
                                                     const float* __restrict__ entt,
                                                     unsigned short* __restrict__ attcat_b,
                                                     float* __restrict__ attn_last,
                                                     float* __restrict__ scal_out) {
    __shared__ char smem[65536];
    char* Kb = smem;          // K staging; role 1 reuses for P^T chunks
    char* VF = smem + 32768;  // role 0: V fragments; role 1: AV fragments

    const int tid = threadIdx.x;
    const int wid = tid >> 6;
    const int lane = tid & 63;
    const int lq = lane & 31;
    const int hi = lane >> 5;

    if (blockIdx.x == 8) {
        if (blockIdx.y || blockIdx.z) return;
        float c = coh[tid], e = entt[tid];
#pragma unroll
        for (int o = 32; o >= 1; o >>= 1) {
            c += __shfl_xor(c, o);
            e += __shfl_xor(e, o);
        }
        float* rc = (float*)smem;
        float* re = rc + 8;
        if (lane == 0) { rc[wid] = c; re[wid] = e; }
        __syncthreads();
        if (tid == 0) {
            float cs = 0.f, es = 0.f;
#pragma unroll
            for (int i = 0; i < 8; i++) { cs += rc[i]; es += re[i]; }
            scal_out[0] = cs / (512.f * 65536.f);
            scal_out[1] = es / 512.f;
        }
        return;
    }

    const int h = blockIdx.x, b = blockIdx.y, role = blockIdx.z;

    // ---- early loads: Q fragments + scale (latency hides under staging/barrier) ----
    short8v qf[4];
    {
        const unsigned short* qbase = aqb + (size_t)(b * 256 + wid * 32 + lq) * 512 + h * 64;
#pragma unroll
        for (int s = 0; s < 4; s++) qf[s] = *(const short8v*)(qbase + (2 * s + hi) * 8);
    }
    const float sq = scale[b * 256 + wid * 32 + lq] * 0.125f;

    // ---- stage K -> Kb (both roles) ----
    {
#pragma unroll
        for (int i = 0; i < 4; i++) {
            int r = wid * 32 + i * 8 + (lane >> 3);
            int lc = (lane & 7) ^ (r & 7);
            gload_lds16(vkb + (size_t)(b * 256 + r) * 512 + h * 64 + lc * 8,
                        Kb + wid * 4096 + i * 1024);
        }
    }

    // ---- stage V (role 0) or AV (role 1) -> VF, same chunk layout ----
    {
        const unsigned short* tsrc = (role == 0) ? vvt : avt;
#pragma unroll
        for (int i = 0; i < 4; i++) {
            gload_lds16(tsrc + (size_t)(h * 64 + 32 * hi + lq) * 512 + b * 256 + 32 * wid + 8 * i,
                        VF + wid * 4096 + i * 1024);
        }
    }
    __syncthreads();

    // ---- QK^T (swapped, 32x32x16): Q from regs, K from LDS ----
    f32x16 p[8] = {};
#pragma unroll
    for (int t = 0; t < 8; t++) {
        const int krow = t * 32 + lq;
#pragma unroll
        for (int s = 0; s < 4; s++) {
            int slot = (2 * s + hi) ^ (krow & 7);
            short8v kf = *(const short8v*)(Kb + krow * 128 + (slot << 4));
            p[t] = __builtin_amdgcn_mfma_f32_32x32x16_bf16(kf, qf[s], p[t], 0, 0, 0);
        }
    }

    // ---- softmax over k ----
    {
        float mx = -1e30f;
#pragma unroll
        for (int t = 0; t < 8; t++) {
            p[t] *= sq;
#pragma unroll
            for (int r = 0; r < 16; r++) mx = fmaxf(mx, p[t][r]);
        }
        mx = fmaxf(mx, __shfl_xor(mx, 32));
        float sum = 0.f;
#pragma unroll
        for (int t = 0; t < 8; t++)
#pragma unroll
            for (int r = 0; r < 16; r++) {
                float e = __expf(p[t][r] - mx);
                p[t][r] = e;
                sum += e;
            }
        sum += __shfl_xor(sum, 32);
        float inv = 1.0f / sum;
#pragma unroll
        for (int t = 0; t < 8; t++) p[t] *= inv;
    }

    if (role == 0) {
        // ---- audio PV: A-frags via cvt_pk + shfl_xor(32); V from VF ----
        f32x16 aacc[2] = {};
#pragma unroll
        for (int t = 0; t < 8; t++) {
            unsigned int c0 = cvtpk_bf16(p[t][0], p[t][1]);
            unsigned int c1 = cvtpk_bf16(p[t][2], p[t][3]);
            unsigned int c2 = cvtpk_bf16(p[t][4], p[t][5]);
            unsigned int c3 = cvtpk_bf16(p[t][6], p[t][7]);
            unsigned int e0 = (unsigned int)__shfl_xor((int)c0, 32);
            unsigned int e1 = (unsigned int)__shfl_xor((int)c1, 32);
            unsigned int e2 = (unsigned int)__shfl_xor((int)c2, 32);
            unsigned int e3 = (unsigned int)__shfl_xor((int)c3, 32);
            W8 fa0;
            fa0.w[0] = hi ? e2 : c0;
            fa0.w[1] = hi ? e3 : c1;
            fa0.w[2] = hi ? c2 : e0;
            fa0.w[3] = hi ? c3 : e1;
            unsigned int c4 = cvtpk_bf16(p[t][8], p[t][9]);
            unsigned int c5 = cvtpk_bf16(p[t][10], p[t][11]);
            unsigned int c6 = cvtpk_bf16(p[t][12], p[t][13]);
            unsigned int c7 = cvtpk_bf16(p[t][14], p[t][15]);
            unsigned int e4 = (unsigned int)__shfl_xor((int)c4, 32);
            unsigned int e5 = (unsigned int)__shfl_xor((int)c5, 32);
            unsigned int e6 = (unsigned int)__shfl_xor((int)c6, 32);
            unsigned int e7 = (unsigned int)__shfl_xor((int)c7, 32);
            W8 fa1;
            fa1.w[0] = hi ? e6 : c4;
            fa1.w[1] = hi ? e7 : c5;
            fa1.w[2] = hi ? c6 : e4;
            fa1.w[3] = hi ? c7 : e5;
#pragma unroll
            for (int dt = 0; dt < 2; dt++) {
                short8v vf = *(const short8v*)(VF + ((((t * 4 + hi) * 2 + dt) * 32 + lq) << 4));
                aacc[dt] = __builtin_amdgcn_mfma_f32_32x32x16_bf16(fa0.v, vf, aacc[dt], 0, 0, 0);
                short8v vg = *(const short8v*)(VF + ((((t * 4 + hi + 2) * 2 + dt) * 32 + lq) << 4));
                aacc[dt] = __builtin_amdgcn_mfma_f32_32x32x16_bf16(fa1.v, vg, aacc[dt], 0, 0, 0);
            }
        }
#pragma unroll
        for (int dt = 0; dt < 2; dt++)
#pragma unroll
            for (int r = 0; r < 16; r++) {
                int qrow = wid * 32 + (r & 3) + 8 * (r >> 2) + 4 * hi;
                attcat_b[(size_t)(b * 256 + qrow) * 512 + h * 64 + 32 * dt + lq] = f2bf(aacc[dt][r]);
            }
        __syncthreads();

        if (h == 7) {
            float* tile = (float*)smem + (size_t)wid * (32 * 33);
            const int q2 = lane >> 1, koff = (lane & 1) * 16;
#pragma unroll
            for (int t = 0; t < 8; t++) {
#pragma unroll
                for (int r = 0; r < 16; r++)
                    tile[lq * 33 + ((r & 3) + 8 * (r >> 2) + 4 * hi)] = p[t][r];
                float* orow = attn_last + (size_t)(b * 256 + wid * 32 + q2) * 256 + 32 * t + koff;
#pragma unroll
                for (int j = 0; j < 16; j++) orow[j] = tile[q2 * 33 + koff + j];
            }
        }
        return;
    }

    // ================= role 1: visual =================
    __syncthreads();  // all QK^T reads of Kb complete

    // ---- write P^T chunk 0 into Kb ----
    if ((wid >> 1) == 0) {
        const int dq = (wid & 1) * 32 + lq;
#pragma unroll
        for (int t = 0; t < 8; t++)
#pragma unroll
            for (int r = 0; r < 16; r++) {
                int k = 32 * t + (r & 3) + 8 * (r >> 2) + 4 * hi;
                int slot = (dq >> 3) ^ ((k ^ (k >> 3)) & 7);
                *(unsigned short*)(Kb + k * 128 + slot * 16 + (dq & 7) * 2) = f2bf(p[t][r]);
            }
    }
    __syncthreads();

    // ---- visual: out[k][d] = sum_q P^T[k][q] AV[q][d]; P^T in Kb, AV in VF ----
    f32x16 vacc[2] = {};
    {
        const int krow = wid * 32 + lq;
        const int xr = (krow ^ (krow >> 3)) & 7;
#pragma unroll
        for (int c = 0; c < 4; c++) {
#pragma unroll
            for (int uc = 0; uc < 4; uc++) {
                int slot = (2 * uc + hi) ^ xr;
                short8v pa = *(const short8v*)(Kb + krow * 128 + slot * 16);
                int m = 2 * (4 * c + uc) + hi;
#pragma unroll
                for (int dt = 0; dt < 2; dt++) {
                    short8v af = *(const short8v*)(VF + (((m * 2 + dt) * 32 + lq) << 4));
                    vacc[dt] = __builtin_amdgcn_mfma_f32_32x32x16_bf16(pa, af, vacc[dt], 0, 0, 0);
                }
            }
            if (c < 3) {
                __syncthreads();
                if ((wid >> 1) == c + 1) {
                    const int dq = (wid & 1) * 32 + lq;
#pragma unroll
                    for (int t = 0; t < 8; t++)
#pragma unroll
                        for (int r = 0; r < 16; r++) {
                            int k = 32 * t + (r & 3) + 8 * (r >> 2) + 4 * hi;
                            int slot = (dq >> 3) ^ ((k ^ (k >> 3)) & 7);
                            *(unsigned short*)(Kb + k * 128 + slot * 16 + (dq & 7) * 2) = f2bf(p[t][r]);
                        }
                }
                __syncthreads();
            }
        }
    }
#pragma unroll
    for (int dt = 0; dt < 2; dt++)
#pragma unroll
        for (int r = 0; r < 16; r++) {
            int krow = wid * 32 + (r & 3) + 8 * (r >> 2) + 4 * hi;
            attcat_b[(size_t)(512 + b * 256 + krow) * 512 + h * 64 + 32 * dt + lq] = f2bf(vacc[dt][r]);
        }
}

// ---------------- residual + LayerNorm ----------------
__global__ __launch_bounds__(256) void ln_final(const float* __restrict__ xa,
                                                const float* __restrict__ xv,
                                                const float* __restrict__ proj,
                                                const float* __restrict__ gamma,
                                                const float* __restrict__ beta,
                                                float* __restrict__ out) {
    __shared__ float red[4];
    const int t = blockIdx.x;
    const int tid = threadIdx.x;
    const int wid = tid >> 6, lane = tid & 63;

    const float* x = (t < 512) ? (xa + t * 512) : (xv + (t - 512) * 512);
    const float* pp = proj + t * 512;

    float y0 = x[tid] + pp[tid];
    float y1 = x[tid + 256] + pp[tid + 256];

    float s = y0 + y1;
#pragma unroll
    for (int o = 32; o >= 1; o >>= 1) s += __shfl_xor(s, o);
    if (lane == 0) red[wid] = s;
    __syncthreads();
    float mean = (red[0] + red[1] + red[2] + red[3]) * (1.f / 512.f);

    float d0 = y0 - mean, d1 = y1 - mean;
    float v = d0 * d0 + d1 * d1;
    __syncthreads();
#pragma unroll
    for (int o = 32; o >= 1; o >>= 1) v += __shfl_xor(v, o);
    if (lane == 0) red[wid] = v;
    __syncthreads();
    float var = (red[0] + red[1] + red[2] + red[3]) * (1.f / 512.f);
    float rstd = rsqrtf(var + 1e-5f);

    out[t * 512 + tid] = d0 * rstd * gamma[tid] + beta[tid];
    out[t * 512 + tid + 256] = d1 * rstd * gamma[tid + 256] + beta[tid + 256];
}

extern "C" void kernel_launch(void* const* d_in, const int* in_sizes, int n_in,
                              void* d_out, int out_size, void* d_ws, size_t ws_size,
                              hipStream_t stream) {
    const float* audio  = (const float*)d_in[0];
    const float* visual = (const float*)d_in[1];
    const float* Wq = (const float*)d_in[2];
    const float* bq = (const float*)d_in[3];
    const float* Wk = (const float*)d_in[4];
    const float* bk = (const float*)d_in[5];
    const float* Wv = (const float*)d_in[6];
    const float* bv = (const float*)d_in[7];
    const float* Wo = (const float*)d_in[8];
    const float* bo = (const float*)d_in[9];
    const float* We = (const float*)d_in[10];
    const float* be = (const float*)d_in[11];
    const float* gamma = (const float*)d_in[12];
    const float* beta  = (const float*)d_in[13];
    float* out = (float*)d_out;

    float* ws = (float*)d_ws;
    float* proj  = ws;                    // 524288 f32
    float* scale = ws + 524288;           // 512
    float* coh   = ws + 524800;           // 512
    float* entt  = ws + 525312;           // 512
    unsigned short* attcat_b = (unsigned short*)(ws + 525824);   // 524288 u16
    unsigned short* audio_b  = (unsigned short*)(ws + 787968);   // 262144 u16
    unsigned short* visual_b = (unsigned short*)(ws + 919040);
    unsigned short* Wqt  = (unsigned short*)(ws + 1050112);
    unsigned short* Wkt  = (unsigned short*)(ws + 1181184);
    unsigned short* Wvt  = (unsigned short*)(ws + 1312256);
    unsigned short* Wot  = (unsigned short*)(ws + 1443328);
    unsigned short* aq_b = (unsigned short*)(ws + 1574400);      // 262144 u16
    unsigned short* vk_b = (unsigned short*)(ws + 1705472);      // 262144 u16
    unsigned short* vvt  = (unsigned short*)(ws + 1836544);      // 262144 u16 [512 d][512 tok]
    unsigned short* avt  = (unsigned short*)(ws + 1967616);      // 262144 u16

    // 0) prep (bf16 + W^T) + token scalar path
    hipLaunchKernelGGL(prep_tok, dim3(1664), dim3(256), 0, stream,
                       audio, visual, Wq, Wk, Wv, Wo, We, be,
                       audio_b, visual_b, Wqt, Wkt, Wvt, Wot,
                       scale, coh, entt);

    // 1) projections (MFMA, BK=512 single-barrier): aq,vk -> bf16; vv,av -> bf16^T [d][tok]
    MfmaArgs g1;
    g1.A[0] = audio_b;  g1.Bt[0] = Wqt; g1.bias[0] = bq; g1.C[0] = aq_b; g1.obf[0] = 1; g1.otr[0] = 0;
    g1.A[1] = visual_b; g1.Bt[1] = Wkt; g1.bias[1] = bk; g1.C[1] = vk_b; g1.obf[1] = 1; g1.otr[1] = 0;
    g1.A[2] = visual_b; g1.Bt[2] = Wvt; g1.bias[2] = bv; g1.C[2] = vvt;  g1.obf[2] = 1; g1.otr[2] = 1;
    g1.A[3] = audio_b;  g1.Bt[3] = Wvt; g1.bias[3] = bv; g1.C[3] = avt;  g1.obf[3] = 1; g1.otr[3] = 1;
    hipLaunchKernelGGL(gemm_mfma, dim3(16, 16, 4), dim3(256), 0, stream, g1);

    // 2) attention role-split (+ scalar block at x==8)
    hipLaunchKernelGGL(attn_roles, dim3(9, 2, 2), dim3(512), 0, stream,
                       aq_b, vk_b, vvt, avt, scale, coh, entt,
                       attcat_b, out + 524290, out + 524288);

    // 3) output projection (MFMA, BK=512): proj = attcat @ Wo + bo   (M=1024, f32 out)
    MfmaArgs g2;
    for (int i = 0; i < 4; i++) {
        g2.A[i] = attcat_b; g2.Bt[i] = Wot; g2.bias[i] = bo; g2.C[i] = proj;
        g2.obf[i] = 0; g2.otr[i] = 0;
    }
    hipLaunchKernelGGL(gemm_mfma, dim3(16, 32, 1), dim3(256), 0, stream, g2);

    // 4) residual + LN
    hipLaunchKernelGGL(ln_final, dim3(1024), dim3(256), 0, stream,
                       audio, visual, proj, gamma, beta, out);
}